// Round 4
// baseline (195.842 us; speedup 1.0000x reference)
//
#include <hip/hip_runtime.h>

#define N_NODES 100000
#define N_EDGES 1600000
#define F 128

#define NB    1563      // buckets of 64 nodes (dst>>6)
#define NBP2  2048      // padded bucket arrays (2/thread at 1024 threads)
#define CAP   1280      // per-bucket capacity: mean 1024, +8 sigma
#define CHUNK 8192      // edges per bin block (run len ~5.2 -> coalesced flush)
#define BCUR  1599      // gcur slot used as the persistent-bucket cursor

#define BIN_BLOCKS   196                 // ceil(1.6M / 8192)
#define HGEMM_BLOCKS 782                 // ceil(100000 / 128)
#define FRONT_GRID_LIN (BIN_BLOCKS + HGEMM_BLOCKS)
#define ACC_GRID     1024                // 4 blocks/CU * 256 CU, bucket-stealing

#define LDP  136
#define SMEM_BYTES 77824                 // max(bin 77824, hgemm 69632)

typedef __bf16  bf16x8 __attribute__((ext_vector_type(8)));
typedef float   f32x4  __attribute__((ext_vector_type(4)));

__device__ inline unsigned short f32_to_bf16(float f) {
    unsigned u = __builtin_bit_cast(unsigned, f);
    u += 0x7FFFu + ((u >> 16) & 1u);     // RNE, finite inputs
    return (unsigned short)(u >> 16);
}
__device__ inline unsigned pack_bf16x2(float lo, float hi) {
    return (unsigned)f32_to_bf16(lo) | ((unsigned)f32_to_bf16(hi) << 16);
}
__device__ inline void addrow(float* acc, const uint4 v) {
    acc[0] += __builtin_bit_cast(float, v.x << 16);
    acc[1] += __builtin_bit_cast(float, v.x & 0xFFFF0000u);
    acc[2] += __builtin_bit_cast(float, v.y << 16);
    acc[3] += __builtin_bit_cast(float, v.y & 0xFFFF0000u);
    acc[4] += __builtin_bit_cast(float, v.z << 16);
    acc[5] += __builtin_bit_cast(float, v.z & 0xFFFF0000u);
    acc[6] += __builtin_bit_cast(float, v.w << 16);
    acc[7] += __builtin_bit_cast(float, v.w & 0xFFFF0000u);
}

// ============ linear-reordered front: bin edges + H = bf16(feat @ W^T) ======
// blocks [0,196): LDS-staged edge binning.
// blocks [196, 196+782): 128-row MFMA tile of H = feat @ W^T, written bf16.
__global__ __launch_bounds__(1024) void gcn_front_lin(
    const float* __restrict__ feat, const float* __restrict__ W,
    const int* __restrict__ src, const int* __restrict__ dst,
    int* __restrict__ gcur, unsigned* __restrict__ bins,
    unsigned short* __restrict__ H)
{
    __shared__ __align__(16) unsigned char smem[SMEM_BYTES];

    const int tid = threadIdx.x;
    const int bx  = blockIdx.x;

    if (bx >= BIN_BLOCKS) {
        // ---------------- H-GEMM body (16 waves, 128x128 tile) -------------
        unsigned short* Alds = (unsigned short*)smem;          // 128*LDP bf16
        unsigned short* Wlds = Alds + 128 * LDP;               // 128*LDP bf16
        const int row0 = (bx - BIN_BLOCKS) * 128;

        #pragma unroll
        for (int i = 0; i < 4; ++i) {                          // W f32 -> bf16 LDS (L2-broadcast)
            const int c = tid + i * 1024;                      // float4 index, 4096 exact
            const int r = c >> 5, cc = c & 31;
            const f32x4 v = *(const f32x4*)(W + (size_t)c * 4);
            uint2 p; p.x = pack_bf16x2(v[0], v[1]); p.y = pack_bf16x2(v[2], v[3]);
            *(uint2*)&Wlds[r * LDP + cc * 4] = p;
        }
        #pragma unroll
        for (int i = 0; i < 4; ++i) {                          // feat f32 -> bf16 LDS
            const int c = tid + i * 1024;
            const int r = c >> 5, cc = c & 31;
            int gr = row0 + r; if (gr > N_NODES - 1) gr = N_NODES - 1;
            const f32x4 v = __builtin_nontemporal_load(
                                 (const f32x4*)(feat + (size_t)gr * F + cc * 4));
            uint2 p; p.x = pack_bf16x2(v[0], v[1]); p.y = pack_bf16x2(v[2], v[3]);
            *(uint2*)&Alds[r * LDP + cc * 4] = p;
        }
        __syncthreads();

        const int lane = tid & 63, wv = tid >> 6;
        const int lr = lane & 15, lq = lane >> 4;
        const int wr = wv & 7;                                 // row tile (16 rows)
        const int wc = wv >> 3;                                // col half (4 n-tiles)

        f32x4 acc[4] = {};
        #pragma unroll
        for (int kk = 0; kk < 4; ++kk) {
            const bf16x8 a = __builtin_bit_cast(bf16x8,
                *(const uint4*)&Alds[(wr * 16 + lr) * LDP + kk * 32 + lq * 8]);
            #pragma unroll
            for (int n2 = 0; n2 < 4; ++n2) {
                const bf16x8 w = __builtin_bit_cast(bf16x8,
                    *(const uint4*)&Wlds[((wc * 4 + n2) * 16 + lr) * LDP + kk * 32 + lq * 8]);
                acc[n2] = __builtin_amdgcn_mfma_f32_16x16x32_bf16(a, w, acc[n2], 0, 0, 0);
            }
        }
        __syncthreads();                                       // all frag reads done

        // stage output tile into Alds (bf16 row-major), then coalesced copy-out
        #pragma unroll
        for (int rg = 0; rg < 4; ++rg) {
            const int r = wr * 16 + lq * 4 + rg;
            #pragma unroll
            for (int n2 = 0; n2 < 4; ++n2)
                Alds[r * LDP + (wc * 4 + n2) * 16 + lr] = f32_to_bf16(acc[n2][rg]);
        }
        __syncthreads();

        #pragma unroll
        for (int i = 0; i < 2; ++i) {
            const int c = tid + i * 1024;                      // 2048 uint4 = 32KB
            const int r = c >> 4, cc = c & 15;
            const int gr = row0 + r;
            if (gr < N_NODES)
                *(uint4*)(H + (size_t)gr * F + cc * 8) = *(const uint4*)&Alds[r * LDP + cc * 8];
        }
        return;
    }

    // ---------------- bin body ----------------
    unsigned*       cnt    = (unsigned*)smem;                  // NBP2
    unsigned*       off    = cnt + NBP2;                       // NBP2
    int*            gbase  = (int*)(off + NBP2);               // NBP2
    unsigned*       staged = (unsigned*)(gbase + NBP2);        // CHUNK
    unsigned short* sbk    = (unsigned short*)(staged + CHUNK);// CHUNK
    unsigned*       scan   = (unsigned*)(sbk + CHUNK);         // 17 used

    const int e0 = bx * CHUNK;

    #pragma unroll
    for (int i = 0; i < 2; ++i) cnt[tid + i * 1024] = 0;
    __syncthreads();

    int sv[8], dv[8];
    #pragma unroll
    for (int i = 0; i < 8; ++i) {
        const int e = e0 + tid + i * 1024;
        if (e < N_EDGES) {
            sv[i] = src[e];
            dv[i] = dst[e];
            atomicAdd(&cnt[dv[i] >> 6], 1u);
        } else dv[i] = -1;
    }
    __syncthreads();

    // shfl-based scan: wave-inclusive + 16 wave bases (2 barriers)
    const int lane = tid & 63, wid = tid >> 6;
    const unsigned s = cnt[2 * tid] + cnt[2 * tid + 1];
    unsigned v = s;
    #pragma unroll
    for (int o = 1; o < 64; o <<= 1) {
        const unsigned t = __shfl_up(v, o, 64);
        if (lane >= o) v += t;
    }
    if (lane == 63) scan[wid] = v;
    __syncthreads();
    if (tid < 16) {
        const unsigned w = scan[tid];
        unsigned x = w;
        #pragma unroll
        for (int o = 1; o < 16; o <<= 1) {
            const unsigned t = __shfl_up(x, o, 16);
            if (tid >= o) x += t;
        }
        scan[tid] = x - w;            // exclusive wave base
        if (tid == 15) scan[16] = x;  // grand total
    }
    __syncthreads();
    const unsigned incl = v + scan[wid];
    const unsigned run  = incl - s;
    off[2 * tid]     = run;
    off[2 * tid + 1] = run + cnt[2 * tid];
    __syncthreads();

    #pragma unroll
    for (int i = 0; i < 8; ++i) {
        if (dv[i] >= 0) {
            const int bk = dv[i] >> 6;
            const unsigned w = (unsigned)sv[i] | ((unsigned)(dv[i] & 63) << 17);
            const unsigned p = atomicAdd(&off[bk], 1u);
            staged[p] = w;
            sbk[p] = (unsigned short)bk;
        }
    }
    __syncthreads();

    #pragma unroll
    for (int i = 0; i < 2; ++i) {
        const int bk = 2 * tid + i;
        if (bk < NB && cnt[bk] > 0)
            gbase[bk] = atomicAdd(&gcur[bk], (int)cnt[bk]);
    }
    __syncthreads();

    const int c_tot = (int)scan[16];
    for (int p = tid; p < c_tot; p += 1024) {
        const int bk = sbk[p];
        const int gp = gbase[bk] + (p - (int)(off[bk] - cnt[bk]));
        if (gp < CAP) bins[(size_t)bk * CAP + gp] = staged[p];
    }
}

// ============ pass 2: persistent bucket-stealing gather of H ===============
__global__ __launch_bounds__(512) void gcn_accum_lin(
    int* __restrict__ gcur,
    const unsigned* __restrict__ bins,
    const unsigned short* __restrict__ H,
    const float* __restrict__ b,
    float* __restrict__ out)
{
    __shared__ unsigned tmp[CAP];
    __shared__ unsigned list[CAP];
    __shared__ int cnt64[64], pos64[64], cur64[64];
    __shared__ int sbkt;
    __shared__ int nextn;

    const int tid  = threadIdx.x;
    const int lane = tid & 63;
    const int sl   = tid & 15;       // feats [8*sl, 8*sl+8)

    const f32x4 b0 = *(const f32x4*)(b + sl * 8);
    const f32x4 b1 = *(const f32x4*)(b + sl * 8 + 4);

    for (;;) {
        __syncthreads();                       // prev iteration fully drained
        if (tid == 0) {
            sbkt  = atomicAdd(&gcur[BCUR], 1);
            nextn = 0;
        }
        __syncthreads();
        const int bkt = sbkt;
        if (bkt >= NB) return;                 // uniform exit

        int c = gcur[bkt]; if (c > CAP) c = CAP;
        const unsigned* bb = bins + (size_t)bkt * CAP;

        for (int i = tid; i < c; i += 512)
            tmp[i] = __builtin_nontemporal_load(bb + i);
        if (tid < 64) cnt64[tid] = 0;
        __syncthreads();

        for (int i = tid; i < c; i += 512) atomicAdd(&cnt64[(tmp[i] >> 17) & 63], 1);
        __syncthreads();

        // single-wave inclusive scan of cnt64 (wave 0, no extra barriers)
        if (tid < 64) {
            const int cv = cnt64[tid];
            int x = cv;
            #pragma unroll
            for (int o = 1; o < 64; o <<= 1) {
                const int t = __shfl_up(x, o, 64);
                if (tid >= o) x += t;
            }
            pos64[tid] = x - cv;
            cur64[tid] = x - cv;
        }
        __syncthreads();

        for (int i = tid; i < c; i += 512) {
            const unsigned w = tmp[i];
            const int p = atomicAdd(&cur64[(w >> 17) & 63], 1);
            list[p] = w;
        }
        __syncthreads();

        const int n0 = bkt * 64;

        // dynamic node assignment: 16-lane groups grab nodes greedily
        for (;;) {
            int myn = 0;
            if (sl == 0) myn = atomicAdd(&nextn, 1);
            myn = __shfl(myn, lane & 48, 64);
            if (myn >= 64) break;

            const int st = pos64[myn];
            const int en = st + cnt64[myn];

            float a0[8] = {0,0,0,0,0,0,0,0};
            float a1[8] = {0,0,0,0,0,0,0,0};
            int k = st;
            for (; k + 7 < en; k += 8) {             // 8 loads in flight
                const unsigned w0 = list[k],     w1 = list[k + 1];
                const unsigned w2 = list[k + 2], w3 = list[k + 3];
                const unsigned w4 = list[k + 4], w5 = list[k + 5];
                const unsigned w6 = list[k + 6], w7 = list[k + 7];
                const uint4 v0 = *(const uint4*)(H + (size_t)(w0 & 0x1FFFF) * F + sl * 8);
                const uint4 v1 = *(const uint4*)(H + (size_t)(w1 & 0x1FFFF) * F + sl * 8);
                const uint4 v2 = *(const uint4*)(H + (size_t)(w2 & 0x1FFFF) * F + sl * 8);
                const uint4 v3 = *(const uint4*)(H + (size_t)(w3 & 0x1FFFF) * F + sl * 8);
                const uint4 v4 = *(const uint4*)(H + (size_t)(w4 & 0x1FFFF) * F + sl * 8);
                const uint4 v5 = *(const uint4*)(H + (size_t)(w5 & 0x1FFFF) * F + sl * 8);
                const uint4 v6 = *(const uint4*)(H + (size_t)(w6 & 0x1FFFF) * F + sl * 8);
                const uint4 v7 = *(const uint4*)(H + (size_t)(w7 & 0x1FFFF) * F + sl * 8);
                addrow(a0, v0); addrow(a1, v1); addrow(a0, v2); addrow(a1, v3);
                addrow(a0, v4); addrow(a1, v5); addrow(a0, v6); addrow(a1, v7);
            }
            for (; k + 3 < en; k += 4) {
                const unsigned w0 = list[k],     w1 = list[k + 1];
                const unsigned w2 = list[k + 2], w3 = list[k + 3];
                const uint4 v0 = *(const uint4*)(H + (size_t)(w0 & 0x1FFFF) * F + sl * 8);
                const uint4 v1 = *(const uint4*)(H + (size_t)(w1 & 0x1FFFF) * F + sl * 8);
                const uint4 v2 = *(const uint4*)(H + (size_t)(w2 & 0x1FFFF) * F + sl * 8);
                const uint4 v3 = *(const uint4*)(H + (size_t)(w3 & 0x1FFFF) * F + sl * 8);
                addrow(a0, v0); addrow(a1, v1); addrow(a0, v2); addrow(a1, v3);
            }
            for (; k < en; ++k) {
                const unsigned w0 = list[k];
                const uint4 v0 = *(const uint4*)(H + (size_t)(w0 & 0x1FFFF) * F + sl * 8);
                addrow(a0, v0);
            }
            #pragma unroll
            for (int q = 0; q < 8; ++q) a0[q] += a1[q];

            const int n = n0 + myn;
            if (n < N_NODES) {
                f32x4 o0, o1;
                o0[0] = fmaxf(a0[0] + b0[0], 0.0f);
                o0[1] = fmaxf(a0[1] + b0[1], 0.0f);
                o0[2] = fmaxf(a0[2] + b0[2], 0.0f);
                o0[3] = fmaxf(a0[3] + b0[3], 0.0f);
                o1[0] = fmaxf(a0[4] + b1[0], 0.0f);
                o1[1] = fmaxf(a0[5] + b1[1], 0.0f);
                o1[2] = fmaxf(a0[6] + b1[2], 0.0f);
                o1[3] = fmaxf(a0[7] + b1[3], 0.0f);
                float* orow = out + (size_t)n * F + sl * 8;
                __builtin_nontemporal_store(o0, (f32x4*)orow);
                __builtin_nontemporal_store(o1, (f32x4*)(orow + 4));
            }
        }
    }
}

// ===================== old 3-kernel path (ws mid-size fallback) =============
#define FEAT_BLOCKS 3125
#define WCONV_BLOCKS 16
#define FRONT_GRID  (BIN_BLOCKS + FEAT_BLOCKS + WCONV_BLOCKS)

__global__ __launch_bounds__(1024) void gcn_front(
    const float* __restrict__ feat, const float* __restrict__ W,
    const int* __restrict__ src, const int* __restrict__ dst,
    int* __restrict__ gcur, unsigned* __restrict__ bins,
    unsigned short* __restrict__ Wbf, float* __restrict__ out)
{
    __shared__ unsigned cnt[NBP2];
    __shared__ unsigned off[NBP2];
    __shared__ int      gbase[NBP2];
    __shared__ unsigned staged[CHUNK];
    __shared__ unsigned short sbk[CHUNK];
    __shared__ unsigned scan[1024];

    const int tid = threadIdx.x;
    const int bx  = blockIdx.x;

    if (bx >= BIN_BLOCKS) {
        const int rb = bx - BIN_BLOCKS;
        if (rb < FEAT_BLOCKS) {
            const int t = rb * 1024 + tid;
            const float4 v = *(const float4*)(feat + (size_t)t * 4);
            uint2 p;
            p.x = pack_bf16x2(v.x, v.y);
            p.y = pack_bf16x2(v.z, v.w);
            const int n = t >> 5, q = t & 31;
            *(uint2*)((char*)out + (size_t)n * 512 + q * 8) = p;
        } else {
            const int i = (rb - FEAT_BLOCKS) * 1024 + tid;
            Wbf[i] = f32_to_bf16(W[i]);
        }
        return;
    }

    const int e0 = bx * CHUNK;

    #pragma unroll
    for (int i = 0; i < 2; ++i) cnt[tid + i * 1024] = 0;
    __syncthreads();

    int sv[8], dv[8];
    #pragma unroll
    for (int i = 0; i < 8; ++i) {
        const int e = e0 + tid + i * 1024;
        if (e < N_EDGES) {
            sv[i] = src[e];
            dv[i] = dst[e];
            atomicAdd(&cnt[dv[i] >> 6], 1u);
        } else dv[i] = -1;
    }
    __syncthreads();

    const unsigned s = cnt[2 * tid] + cnt[2 * tid + 1];
    scan[tid] = s;
    __syncthreads();
    for (int o = 1; o < 1024; o <<= 1) {
        const unsigned t = (tid >= o) ? scan[tid - o] : 0;
        __syncthreads();
        scan[tid] += t;
        __syncthreads();
    }
    const unsigned run = scan[tid] - s;
    off[2 * tid]     = run;
    off[2 * tid + 1] = run + cnt[2 * tid];
    __syncthreads();

    #pragma unroll
    for (int i = 0; i < 8; ++i) {
        if (dv[i] >= 0) {
            const int bk = dv[i] >> 6;
            const unsigned w = (unsigned)sv[i] | ((unsigned)(dv[i] & 63) << 17);
            const unsigned p = atomicAdd(&off[bk], 1u);
            staged[p] = w;
            sbk[p] = (unsigned short)bk;
        }
    }
    __syncthreads();

    #pragma unroll
    for (int i = 0; i < 2; ++i) {
        const int bk = 2 * tid + i;
        if (bk < NB && cnt[bk] > 0)
            gbase[bk] = atomicAdd(&gcur[bk], (int)cnt[bk]);
    }
    __syncthreads();

    const int c_tot = (int)scan[1023];
    for (int p = tid; p < c_tot; p += 1024) {
        const int bk = sbk[p];
        const int gp = gbase[bk] + (p - (int)(off[bk] - cnt[bk]));
        if (gp < CAP) bins[(size_t)bk * CAP + gp] = staged[p];
    }
}

__global__ __launch_bounds__(512) void gcn_accum2(
    const int* __restrict__ gcur,
    const unsigned* __restrict__ bins,
    float* __restrict__ out)
{
    __shared__ unsigned tmp[CAP];
    __shared__ unsigned list[CAP];
    __shared__ int cnt64[64], scn[64], pos64[64], cur64[64];

    const int tid = threadIdx.x;
    const int bkt = blockIdx.x;

    int c = gcur[bkt]; if (c > CAP) c = CAP;
    const unsigned* bb = bins + (size_t)bkt * CAP;

    for (int i = tid; i < c; i += 512) tmp[i] = bb[i];
    if (tid < 64) cnt64[tid] = 0;
    __syncthreads();

    for (int i = tid; i < c; i += 512) atomicAdd(&cnt64[(tmp[i] >> 17) & 63], 1);
    __syncthreads();

    if (tid < 64) scn[tid] = cnt64[tid];
    __syncthreads();
    #pragma unroll
    for (int o = 1; o < 64; o <<= 1) {
        int t = 0;
        if (tid < 64 && tid >= o) t = scn[tid - o];
        __syncthreads();
        if (tid < 64) scn[tid] += t;
        __syncthreads();
    }
    if (tid < 64) {
        const int st = scn[tid] - cnt64[tid];
        pos64[tid] = st;
        cur64[tid] = st;
    }
    __syncthreads();

    for (int i = tid; i < c; i += 512) {
        const unsigned w = tmp[i];
        const int p = atomicAdd(&cur64[(w >> 17) & 63], 1);
        list[p] = w;
    }
    __syncthreads();

    const int grp = tid >> 4;
    const int sl  = tid & 15;
    const int n0  = bkt * 64;

    #pragma unroll
    for (int ni = 0; ni < 2; ++ni) {
        const int l  = grp * 2 + ni;
        const int st = pos64[l];
        const int en = st + cnt64[l];

        float a0[8] = {0,0,0,0,0,0,0,0};
        float a1[8] = {0,0,0,0,0,0,0,0};
        int k = st;
        for (; k + 3 < en; k += 4) {
            const unsigned w0 = list[k],     w1 = list[k + 1];
            const unsigned w2 = list[k + 2], w3 = list[k + 3];
            const uint4 v0 = *(const uint4*)((const char*)out + (size_t)(w0 & 0x1FFFF) * 512 + sl * 16);
            const uint4 v1 = *(const uint4*)((const char*)out + (size_t)(w1 & 0x1FFFF) * 512 + sl * 16);
            const uint4 v2 = *(const uint4*)((const char*)out + (size_t)(w2 & 0x1FFFF) * 512 + sl * 16);
            const uint4 v3 = *(const uint4*)((const char*)out + (size_t)(w3 & 0x1FFFF) * 512 + sl * 16);
            addrow(a0, v0); addrow(a1, v1); addrow(a0, v2); addrow(a1, v3);
        }
        for (; k < en; ++k) {
            const unsigned w0 = list[k];
            const uint4 v0 = *(const uint4*)((const char*)out + (size_t)(w0 & 0x1FFFF) * 512 + sl * 16);
            addrow(a0, v0);
        }
        #pragma unroll
        for (int q = 0; q < 8; ++q) a0[q] += a1[q];

        const int n = n0 + l;
        if (n < N_NODES) {
            uint4 o;
            o.x = pack_bf16x2(a0[0], a0[1]);
            o.y = pack_bf16x2(a0[2], a0[3]);
            o.z = pack_bf16x2(a0[4], a0[5]);
            o.w = pack_bf16x2(a0[6], a0[7]);
            *(uint4*)((char*)out + (size_t)n * 512 + 256 + sl * 16) = o;
        }
    }
}

#define MT   128

__global__ __launch_bounds__(256) void gcn_gemm_mfma(
    float* __restrict__ out,
    const unsigned short* __restrict__ Wbf,
    const float* __restrict__ b)
{
    __shared__ unsigned short Alds[MT * LDP];
    __shared__ unsigned short Wlds[F * LDP];

    const int tid  = threadIdx.x;
    const int row0 = blockIdx.x * MT;

    #pragma unroll
    for (int i = 0; i < 8; ++i) {
        const int c = tid + i * 256;
        const int r = c >> 4, cc = c & 15;
        *(uint4*)&Wlds[r * LDP + cc * 8] = *(const uint4*)&Wbf[c * 8];
    }
    #pragma unroll
    for (int i = 0; i < 8; ++i) {
        const int c = tid + i * 256;
        const int r = c >> 4, cc = c & 15;
        int gr = row0 + r; if (gr > N_NODES - 1) gr = N_NODES - 1;
        const uint4 v = *(const uint4*)((const char*)out + (size_t)gr * 512 + 256 + cc * 16);
        *(uint4*)&Alds[r * LDP + cc * 8] = v;
    }
    __syncthreads();

    const int lane = tid & 63;
    const int wv   = tid >> 6;
    const int lr   = lane & 15;
    const int lq   = lane >> 4;

    f32x4 acc[2][8] = {};
    #pragma unroll
    for (int kk = 0; kk < 4; ++kk) {
        bf16x8 a[2], w[8];
        #pragma unroll
        for (int i = 0; i < 2; ++i)
            a[i] = __builtin_bit_cast(bf16x8,
                *(const uint4*)&Alds[(wv * 32 + i * 16 + lr) * LDP + kk * 32 + lq * 8]);
        #pragma unroll
        for (int n = 0; n < 8; ++n)
            w[n] = __builtin_bit_cast(bf16x8,
                *(const uint4*)&Wlds[(n * 16 + lr) * LDP + kk * 32 + lq * 8]);
        #pragma unroll
        for (int i = 0; i < 2; ++i)
            #pragma unroll
            for (int n = 0; n < 8; ++n)
                acc[i][n] = __builtin_amdgcn_mfma_f32_16x16x32_bf16(a[i], w[n], acc[i][n], 0, 0, 0);
    }

    float bias[8];
    #pragma unroll
    for (int n = 0; n < 8; ++n) bias[n] = b[n * 16 + lr];

    #pragma unroll
    for (int i = 0; i < 2; ++i) {
        const int rbase = wv * 32 + i * 16 + lq * 4;
        #pragma unroll
        for (int rg = 0; rg < 4; ++rg) {
            const int gr = row0 + rbase + rg;
            if (gr < N_NODES) {
                float* orow = out + (size_t)gr * F;
                #pragma unroll
                for (int n = 0; n < 8; ++n) {
                    const float v = acc[i][n][rg] + bias[n];
                    orow[n * 16 + lr] = v > 0.0f ? v : 0.0f;
                }
            }
        }
    }
}

// ===================== fallback path (ws too small) =========================
__global__ __launch_bounds__(256) void gcn_scatter(
    const float* __restrict__ feat,
    const int* __restrict__ src, const int* __restrict__ dst,
    float* __restrict__ agg)
{
    const int sub  = threadIdx.x >> 5;
    const int lane = threadIdx.x & 31;
    const long long e = (long long)blockIdx.x * 8 + sub;
    if (e >= N_EDGES) return;
    const int s = src[e], d = dst[e];
    const float4 v = *(const float4*)(feat + (size_t)s * F + lane * 4);
    float* ar = agg + (size_t)d * F + lane * 4;
    unsafeAtomicAdd(ar + 0, v.x);
    unsafeAtomicAdd(ar + 1, v.y);
    unsafeAtomicAdd(ar + 2, v.z);
    unsafeAtomicAdd(ar + 3, v.w);
}

#define GR  64
#define LDW 132
__global__ __launch_bounds__(256) void gcn_gemm_relu(
    float* __restrict__ agg_out,
    const float* __restrict__ W, const float* __restrict__ b)
{
    __shared__ float Wl[F][LDW];
    __shared__ float At[GR][LDW];
    const int tid = threadIdx.x;
    const long long row0 = (long long)blockIdx.x * GR;
    #pragma unroll
    for (int i = 0; i < 64; ++i) {
        const int e = tid + i * 256;
        Wl[e >> 7][e & 127] = W[e];
    }
    #pragma unroll
    for (int i = 0; i < 32; ++i) {
        const int e = tid + i * 256;
        const int r = e >> 7, k2 = e & 127;
        const long long gr = row0 + r;
        At[r][k2] = (gr < N_NODES) ? agg_out[gr * F + k2] : 0.0f;
    }
    __syncthreads();
    const int tx = tid & 15, ty = tid >> 4, r0 = ty * 4;
    float acc[4][8];
    #pragma unroll
    for (int r = 0; r < 4; ++r)
        #pragma unroll
        for (int m = 0; m < 8; ++m) acc[r][m] = 0.0f;
    for (int k0 = 0; k0 < F; k0 += 4) {
        float4 a[4], w[8];
        #pragma unroll
        for (int r = 0; r < 4; ++r) a[r] = *(const float4*)&At[r0 + r][k0];
        #pragma unroll
        for (int m = 0; m < 8; ++m) w[m] = *(const float4*)&Wl[tx + 16 * m][k0];
        #pragma unroll
        for (int r = 0; r < 4; ++r)
            #pragma unroll
            for (int m = 0; m < 8; ++m)
                acc[r][m] += a[r].x * w[m].x + a[r].y * w[m].y
                           + a[r].z * w[m].z + a[r].w * w[m].w;
    }
    float bias[8];
    #pragma unroll
    for (int m = 0; m < 8; ++m) bias[m] = b[tx + 16 * m];
    __syncthreads();
    #pragma unroll
    for (int r = 0; r < 4; ++r) {
        const long long gr = row0 + r0 + r;
        if (gr < N_NODES) {
            float* orow = agg_out + gr * F;
            #pragma unroll
            for (int m = 0; m < 8; ++m) {
                const float v = acc[r][m] + bias[m];
                orow[tx + 16 * m] = v > 0.0f ? v : 0.0f;
            }
        }
    }
}

extern "C" void kernel_launch(void* const* d_in, const int* in_sizes, int n_in,
                              void* d_out, int out_size, void* d_ws, size_t ws_size,
                              hipStream_t stream) {
    const float* feat = (const float*)d_in[0];
    const int*   src  = (const int*)d_in[1];
    const int*   dst  = (const int*)d_in[2];
    const float* W    = (const float*)d_in[3];
    const float* b    = (const float*)d_in[4];
    float* out = (float*)d_out;

    // lin path ws: gcur[1600 ints, slot 1599 = bucket cursor] | bins | H[N*F bf16]
    const size_t ws_lin = 1600u * 4 + (size_t)NB * CAP * 4 + (size_t)N_NODES * F * 2;
    // old path: gcur | bins | Wbf
    const size_t ws_old = 1600u * 4 + (size_t)NB * CAP * 4 + (size_t)F * F * 2;

    if (ws_size >= ws_lin) {
        int* gcur = (int*)d_ws;
        unsigned* bins = (unsigned*)(gcur + 1600);
        unsigned short* H = (unsigned short*)(bins + (size_t)NB * CAP);

        hipMemsetAsync(gcur, 0, 1600 * sizeof(int), stream);
        gcn_front_lin<<<FRONT_GRID_LIN, 1024, 0, stream>>>(feat, W, src, dst, gcur, bins, H);
        gcn_accum_lin<<<ACC_GRID, 512, 0, stream>>>(gcur, bins, H, b, out);
    } else if (ws_size >= ws_old) {
        int* gcur = (int*)d_ws;
        unsigned* bins = (unsigned*)(gcur + 1600);
        unsigned short* Wbf = (unsigned short*)(bins + (size_t)NB * CAP);

        hipMemsetAsync(gcur, 0, NB * sizeof(int), stream);
        gcn_front   <<<FRONT_GRID, 1024, 0, stream>>>(feat, W, src, dst, gcur, bins, Wbf, out);
        gcn_accum2  <<<NB, 512, 0, stream>>>(gcur, bins, out);
        gcn_gemm_mfma<<<(N_NODES + MT - 1) / MT, 256, 0, stream>>>(out, Wbf, b);
    } else {
        hipMemsetAsync(out, 0, (size_t)N_NODES * F * sizeof(float), stream);
        gcn_scatter<<<N_EDGES / 8, 256, 0, stream>>>(feat, src, dst, out);
        gcn_gemm_relu<<<(N_NODES + GR - 1) / GR, 256, 0, stream>>>(out, W, b);
    }
}

// Round 5
// 194.524 us; speedup vs baseline: 1.0068x; 1.0068x over previous
//
#include <hip/hip_runtime.h>

#define N_NODES 100000
#define N_EDGES 1600000
#define F 128

#define NB    1563      // buckets of 64 nodes (dst>>6)
#define NBP2  2048      // padded bucket arrays (2/thread at 1024 threads)
#define CAP   1280      // per-bucket capacity: mean 1024, +8 sigma
#define CHUNK 8192      // edges per bin block (run len ~5.2 -> coalesced flush)

#define BIN_BLOCKS   196                 // ceil(1.6M / 8192)
#define HGEMM_BLOCKS 782                 // ceil(100000 / 128)

#define LDP  136

typedef __bf16  bf16x8 __attribute__((ext_vector_type(8)));
typedef float   f32x4  __attribute__((ext_vector_type(4)));

__device__ inline unsigned short f32_to_bf16(float f) {
    unsigned u = __builtin_bit_cast(unsigned, f);
    u += 0x7FFFu + ((u >> 16) & 1u);     // RNE, finite inputs
    return (unsigned short)(u >> 16);
}
__device__ inline unsigned pack_bf16x2(float lo, float hi) {
    return (unsigned)f32_to_bf16(lo) | ((unsigned)f32_to_bf16(hi) << 16);
}
__device__ inline void addrow(float* acc, const uint4 v) {
    acc[0] += __builtin_bit_cast(float, v.x << 16);
    acc[1] += __builtin_bit_cast(float, v.x & 0xFFFF0000u);
    acc[2] += __builtin_bit_cast(float, v.y << 16);
    acc[3] += __builtin_bit_cast(float, v.y & 0xFFFF0000u);
    acc[4] += __builtin_bit_cast(float, v.z << 16);
    acc[5] += __builtin_bit_cast(float, v.z & 0xFFFF0000u);
    acc[6] += __builtin_bit_cast(float, v.w << 16);
    acc[7] += __builtin_bit_cast(float, v.w & 0xFFFF0000u);
}

// ============ init: zero cursors + preconvert W to bf16 =====================
__global__ __launch_bounds__(1024) void gcn_init(
    const float* __restrict__ W, unsigned short* __restrict__ Wbf,
    int* __restrict__ gcur)
{
    const int i = blockIdx.x * 1024 + threadIdx.x;     // 16 blocks -> 16384 exact
    Wbf[i] = f32_to_bf16(W[i]);
    if (i < 1600) gcur[i] = 0;
}

// ============ edge binning (separate dispatch for attribution) ==============
__global__ __launch_bounds__(1024) void gcn_bin(
    const int* __restrict__ src, const int* __restrict__ dst,
    int* __restrict__ gcur, unsigned* __restrict__ bins)
{
    __shared__ unsigned cnt[NBP2];
    __shared__ unsigned off[NBP2];
    __shared__ int      gbase[NBP2];
    __shared__ unsigned staged[CHUNK];
    __shared__ unsigned short sbk[CHUNK];
    __shared__ unsigned scan[32];

    const int tid = threadIdx.x;
    const int e0  = blockIdx.x * CHUNK;

    #pragma unroll
    for (int i = 0; i < 2; ++i) cnt[tid + i * 1024] = 0;
    __syncthreads();

    int sv[8], dv[8];
    #pragma unroll
    for (int i = 0; i < 8; ++i) {
        const int e = e0 + tid + i * 1024;
        if (e < N_EDGES) {
            sv[i] = src[e];
            dv[i] = dst[e];
            atomicAdd(&cnt[dv[i] >> 6], 1u);
        } else dv[i] = -1;
    }
    __syncthreads();

    // shfl-based scan: wave-inclusive + 16 wave bases (2 barriers)
    const int lane = tid & 63, wid = tid >> 6;
    const unsigned s = cnt[2 * tid] + cnt[2 * tid + 1];
    unsigned v = s;
    #pragma unroll
    for (int o = 1; o < 64; o <<= 1) {
        const unsigned t = __shfl_up(v, o, 64);
        if (lane >= o) v += t;
    }
    if (lane == 63) scan[wid] = v;
    __syncthreads();
    if (tid < 16) {
        const unsigned w = scan[tid];
        unsigned x = w;
        #pragma unroll
        for (int o = 1; o < 16; o <<= 1) {
            const unsigned t = __shfl_up(x, o, 16);
            if (tid >= o) x += t;
        }
        scan[tid] = x - w;            // exclusive wave base
        if (tid == 15) scan[16] = x;  // grand total
    }
    __syncthreads();
    const unsigned incl = v + scan[wid];
    const unsigned run  = incl - s;
    off[2 * tid]     = run;
    off[2 * tid + 1] = run + cnt[2 * tid];
    __syncthreads();

    #pragma unroll
    for (int i = 0; i < 8; ++i) {
        if (dv[i] >= 0) {
            const int bk = dv[i] >> 6;
            const unsigned w = (unsigned)sv[i] | ((unsigned)(dv[i] & 63) << 17);
            const unsigned p = atomicAdd(&off[bk], 1u);
            staged[p] = w;
            sbk[p] = (unsigned short)bk;
        }
    }
    __syncthreads();

    #pragma unroll
    for (int i = 0; i < 2; ++i) {
        const int bk = 2 * tid + i;
        if (bk < NB && cnt[bk] > 0)
            gbase[bk] = atomicAdd(&gcur[bk], (int)cnt[bk]);
    }
    __syncthreads();

    const int c_tot = (int)scan[16];
    for (int p = tid; p < c_tot; p += 1024) {
        const int bk = sbk[p];
        const int gp = gbase[bk] + (p - (int)(off[bk] - cnt[bk]));
        if (gp < CAP) bins[(size_t)bk * CAP + gp] = staged[p];
    }
}

// ============ H = bf16(feat @ W^T), 128-row MFMA tiles ======================
__global__ __launch_bounds__(1024) void gcn_hgemm(
    const float* __restrict__ feat, const unsigned short* __restrict__ Wbf,
    unsigned short* __restrict__ H)
{
    __shared__ unsigned short Alds[128 * LDP];
    __shared__ unsigned short Wlds[128 * LDP];

    const int tid  = threadIdx.x;
    const int row0 = blockIdx.x * 128;

    #pragma unroll
    for (int i = 0; i < 2; ++i) {                          // Wbf -> LDS (vector)
        const int c = tid + i * 1024;                      // uint4 index
        const int r = c >> 4, cc = c & 15;
        *(uint4*)&Wlds[r * LDP + cc * 8] = *(const uint4*)&Wbf[c * 8];
    }
    #pragma unroll
    for (int i = 0; i < 4; ++i) {                          // feat f32 -> bf16 LDS
        const int c = tid + i * 1024;
        const int r = c >> 5, cc = c & 31;
        int gr = row0 + r; if (gr > N_NODES - 1) gr = N_NODES - 1;
        const f32x4 v = *(const f32x4*)(feat + (size_t)gr * F + cc * 4);
        uint2 p; p.x = pack_bf16x2(v[0], v[1]); p.y = pack_bf16x2(v[2], v[3]);
        *(uint2*)&Alds[r * LDP + cc * 4] = p;
    }
    __syncthreads();

    const int lane = tid & 63, wv = tid >> 6;
    const int lr = lane & 15, lq = lane >> 4;
    const int wr = wv & 7;                                 // row tile (16 rows)
    const int wc = wv >> 3;                                // col half (4 n-tiles)

    f32x4 acc[4] = {};
    #pragma unroll
    for (int kk = 0; kk < 4; ++kk) {
        const bf16x8 a = __builtin_bit_cast(bf16x8,
            *(const uint4*)&Alds[(wr * 16 + lr) * LDP + kk * 32 + lq * 8]);
        #pragma unroll
        for (int n2 = 0; n2 < 4; ++n2) {
            const bf16x8 w = __builtin_bit_cast(bf16x8,
                *(const uint4*)&Wlds[((wc * 4 + n2) * 16 + lr) * LDP + kk * 32 + lq * 8]);
            acc[n2] = __builtin_amdgcn_mfma_f32_16x16x32_bf16(a, w, acc[n2], 0, 0, 0);
        }
    }
    __syncthreads();                                       // all frag reads done

    // stage output tile into Alds (bf16 row-major), then coalesced copy-out
    #pragma unroll
    for (int rg = 0; rg < 4; ++rg) {
        const int r = wr * 16 + lq * 4 + rg;
        #pragma unroll
        for (int n2 = 0; n2 < 4; ++n2)
            Alds[r * LDP + (wc * 4 + n2) * 16 + lr] = f32_to_bf16(acc[n2][rg]);
    }
    __syncthreads();

    #pragma unroll
    for (int i = 0; i < 2; ++i) {
        const int c = tid + i * 1024;                      // 2048 uint4 = 32KB
        const int r = c >> 4, cc = c & 15;
        const int gr = row0 + r;
        if (gr < N_NODES)
            *(uint4*)(H + (size_t)gr * F + cc * 8) = *(const uint4*)&Alds[r * LDP + cc * 8];
    }
}

// ============ pass 2: counting-sort + gather of H + bias + ReLU =============
__global__ __launch_bounds__(512) void gcn_accum_lin(
    const int* __restrict__ gcur,
    const unsigned* __restrict__ bins,
    const unsigned short* __restrict__ H,
    const float* __restrict__ b,
    float* __restrict__ out)
{
    __shared__ unsigned tmp[CAP];
    __shared__ unsigned list[CAP];
    __shared__ int cnt64[64], pos64[64], cur64[64];
    __shared__ int nextn;

    const int tid  = threadIdx.x;
    const int bkt  = blockIdx.x;
    const int lane = tid & 63;
    const int sl   = tid & 15;       // feats [8*sl, 8*sl+8)

    int c = gcur[bkt]; if (c > CAP) c = CAP;
    const unsigned* bb = bins + (size_t)bkt * CAP;

    for (int i = tid; i < c; i += 512) tmp[i] = bb[i];
    if (tid < 64) cnt64[tid] = 0;
    if (tid == 0) nextn = 0;
    __syncthreads();

    for (int i = tid; i < c; i += 512) atomicAdd(&cnt64[(tmp[i] >> 17) & 63], 1);
    __syncthreads();

    // single-wave inclusive scan of cnt64 (wave 0)
    if (tid < 64) {
        const int cv = cnt64[tid];
        int x = cv;
        #pragma unroll
        for (int o = 1; o < 64; o <<= 1) {
            const int t = __shfl_up(x, o, 64);
            if (tid >= o) x += t;
        }
        pos64[tid] = x - cv;
        cur64[tid] = x - cv;
    }
    __syncthreads();

    for (int i = tid; i < c; i += 512) {
        const unsigned w = tmp[i];
        const int p = atomicAdd(&cur64[(w >> 17) & 63], 1);
        list[p] = w;
    }
    __syncthreads();

    const int n0 = bkt * 64;

    const f32x4 b0 = *(const f32x4*)(b + sl * 8);
    const f32x4 b1 = *(const f32x4*)(b + sl * 8 + 4);

    // dynamic node assignment: 16-lane groups grab nodes greedily
    for (;;) {
        int myn = 0;
        if (sl == 0) myn = atomicAdd(&nextn, 1);
        myn = __shfl(myn, lane & 48, 64);
        if (myn >= 64) break;

        const int st = pos64[myn];
        const int en = st + cnt64[myn];

        float a0[8] = {0,0,0,0,0,0,0,0};
        float a1[8] = {0,0,0,0,0,0,0,0};
        int k = st;
        for (; k + 7 < en; k += 8) {             // 8 loads in flight
            const unsigned w0 = list[k],     w1 = list[k + 1];
            const unsigned w2 = list[k + 2], w3 = list[k + 3];
            const unsigned w4 = list[k + 4], w5 = list[k + 5];
            const unsigned w6 = list[k + 6], w7 = list[k + 7];
            const uint4 v0 = *(const uint4*)(H + (size_t)(w0 & 0x1FFFF) * F + sl * 8);
            const uint4 v1 = *(const uint4*)(H + (size_t)(w1 & 0x1FFFF) * F + sl * 8);
            const uint4 v2 = *(const uint4*)(H + (size_t)(w2 & 0x1FFFF) * F + sl * 8);
            const uint4 v3 = *(const uint4*)(H + (size_t)(w3 & 0x1FFFF) * F + sl * 8);
            const uint4 v4 = *(const uint4*)(H + (size_t)(w4 & 0x1FFFF) * F + sl * 8);
            const uint4 v5 = *(const uint4*)(H + (size_t)(w5 & 0x1FFFF) * F + sl * 8);
            const uint4 v6 = *(const uint4*)(H + (size_t)(w6 & 0x1FFFF) * F + sl * 8);
            const uint4 v7 = *(const uint4*)(H + (size_t)(w7 & 0x1FFFF) * F + sl * 8);
            addrow(a0, v0); addrow(a1, v1); addrow(a0, v2); addrow(a1, v3);
            addrow(a0, v4); addrow(a1, v5); addrow(a0, v6); addrow(a1, v7);
        }
        for (; k + 3 < en; k += 4) {
            const unsigned w0 = list[k],     w1 = list[k + 1];
            const unsigned w2 = list[k + 2], w3 = list[k + 3];
            const uint4 v0 = *(const uint4*)(H + (size_t)(w0 & 0x1FFFF) * F + sl * 8);
            const uint4 v1 = *(const uint4*)(H + (size_t)(w1 & 0x1FFFF) * F + sl * 8);
            const uint4 v2 = *(const uint4*)(H + (size_t)(w2 & 0x1FFFF) * F + sl * 8);
            const uint4 v3 = *(const uint4*)(H + (size_t)(w3 & 0x1FFFF) * F + sl * 8);
            addrow(a0, v0); addrow(a1, v1); addrow(a0, v2); addrow(a1, v3);
        }
        for (; k < en; ++k) {
            const unsigned w0 = list[k];
            const uint4 v0 = *(const uint4*)(H + (size_t)(w0 & 0x1FFFF) * F + sl * 8);
            addrow(a0, v0);
        }
        #pragma unroll
        for (int q = 0; q < 8; ++q) a0[q] += a1[q];

        const int n = n0 + myn;
        if (n < N_NODES) {
            f32x4 o0, o1;
            o0[0] = fmaxf(a0[0] + b0[0], 0.0f);
            o0[1] = fmaxf(a0[1] + b0[1], 0.0f);
            o0[2] = fmaxf(a0[2] + b0[2], 0.0f);
            o0[3] = fmaxf(a0[3] + b0[3], 0.0f);
            o1[0] = fmaxf(a0[4] + b1[0], 0.0f);
            o1[1] = fmaxf(a0[5] + b1[1], 0.0f);
            o1[2] = fmaxf(a0[6] + b1[2], 0.0f);
            o1[3] = fmaxf(a0[7] + b1[3], 0.0f);
            float* orow = out + (size_t)n * F + sl * 8;
            *(f32x4*)orow = o0;
            *(f32x4*)(orow + 4) = o1;
        }
    }
}

// ===================== old 3-kernel path (ws mid-size fallback) =============
#define FEAT_BLOCKS 3125
#define WCONV_BLOCKS 16
#define FRONT_GRID  (BIN_BLOCKS + FEAT_BLOCKS + WCONV_BLOCKS)

__global__ __launch_bounds__(1024) void gcn_front(
    const float* __restrict__ feat, const float* __restrict__ W,
    const int* __restrict__ src, const int* __restrict__ dst,
    int* __restrict__ gcur, unsigned* __restrict__ bins,
    unsigned short* __restrict__ Wbf, float* __restrict__ out)
{
    __shared__ unsigned cnt[NBP2];
    __shared__ unsigned off[NBP2];
    __shared__ int      gbase[NBP2];
    __shared__ unsigned staged[CHUNK];
    __shared__ unsigned short sbk[CHUNK];
    __shared__ unsigned scan[1024];

    const int tid = threadIdx.x;
    const int bx  = blockIdx.x;

    if (bx >= BIN_BLOCKS) {
        const int rb = bx - BIN_BLOCKS;
        if (rb < FEAT_BLOCKS) {
            const int t = rb * 1024 + tid;
            const float4 v = *(const float4*)(feat + (size_t)t * 4);
            uint2 p;
            p.x = pack_bf16x2(v.x, v.y);
            p.y = pack_bf16x2(v.z, v.w);
            const int n = t >> 5, q = t & 31;
            *(uint2*)((char*)out + (size_t)n * 512 + q * 8) = p;
        } else {
            const int i = (rb - FEAT_BLOCKS) * 1024 + tid;
            Wbf[i] = f32_to_bf16(W[i]);
        }
        return;
    }

    const int e0 = bx * CHUNK;

    #pragma unroll
    for (int i = 0; i < 2; ++i) cnt[tid + i * 1024] = 0;
    __syncthreads();

    int sv[8], dv[8];
    #pragma unroll
    for (int i = 0; i < 8; ++i) {
        const int e = e0 + tid + i * 1024;
        if (e < N_EDGES) {
            sv[i] = src[e];
            dv[i] = dst[e];
            atomicAdd(&cnt[dv[i] >> 6], 1u);
        } else dv[i] = -1;
    }
    __syncthreads();

    const unsigned s = cnt[2 * tid] + cnt[2 * tid + 1];
    scan[tid] = s;
    __syncthreads();
    for (int o = 1; o < 1024; o <<= 1) {
        const unsigned t = (tid >= o) ? scan[tid - o] : 0;
        __syncthreads();
        scan[tid] += t;
        __syncthreads();
    }
    const unsigned run = scan[tid] - s;
    off[2 * tid]     = run;
    off[2 * tid + 1] = run + cnt[2 * tid];
    __syncthreads();

    #pragma unroll
    for (int i = 0; i < 8; ++i) {
        if (dv[i] >= 0) {
            const int bk = dv[i] >> 6;
            const unsigned w = (unsigned)sv[i] | ((unsigned)(dv[i] & 63) << 17);
            const unsigned p = atomicAdd(&off[bk], 1u);
            staged[p] = w;
            sbk[p] = (unsigned short)bk;
        }
    }
    __syncthreads();

    #pragma unroll
    for (int i = 0; i < 2; ++i) {
        const int bk = 2 * tid + i;
        if (bk < NB && cnt[bk] > 0)
            gbase[bk] = atomicAdd(&gcur[bk], (int)cnt[bk]);
    }
    __syncthreads();

    const int c_tot = (int)scan[1023];
    for (int p = tid; p < c_tot; p += 1024) {
        const int bk = sbk[p];
        const int gp = gbase[bk] + (p - (int)(off[bk] - cnt[bk]));
        if (gp < CAP) bins[(size_t)bk * CAP + gp] = staged[p];
    }
}

__global__ __launch_bounds__(512) void gcn_accum2(
    const int* __restrict__ gcur,
    const unsigned* __restrict__ bins,
    float* __restrict__ out)
{
    __shared__ unsigned tmp[CAP];
    __shared__ unsigned list[CAP];
    __shared__ int cnt64[64], scn[64], pos64[64], cur64[64];

    const int tid = threadIdx.x;
    const int bkt = blockIdx.x;

    int c = gcur[bkt]; if (c > CAP) c = CAP;
    const unsigned* bb = bins + (size_t)bkt * CAP;

    for (int i = tid; i < c; i += 512) tmp[i] = bb[i];
    if (tid < 64) cnt64[tid] = 0;
    __syncthreads();

    for (int i = tid; i < c; i += 512) atomicAdd(&cnt64[(tmp[i] >> 17) & 63], 1);
    __syncthreads();

    if (tid < 64) scn[tid] = cnt64[tid];
    __syncthreads();
    #pragma unroll
    for (int o = 1; o < 64; o <<= 1) {
        int t = 0;
        if (tid < 64 && tid >= o) t = scn[tid - o];
        __syncthreads();
        if (tid < 64) scn[tid] += t;
        __syncthreads();
    }
    if (tid < 64) {
        const int st = scn[tid] - cnt64[tid];
        pos64[tid] = st;
        cur64[tid] = st;
    }
    __syncthreads();

    for (int i = tid; i < c; i += 512) {
        const unsigned w = tmp[i];
        const int p = atomicAdd(&cur64[(w >> 17) & 63], 1);
        list[p] = w;
    }
    __syncthreads();

    const int grp = tid >> 4;
    const int sl  = tid & 15;
    const int n0  = bkt * 64;

    #pragma unroll
    for (int ni = 0; ni < 2; ++ni) {
        const int l  = grp * 2 + ni;
        const int st = pos64[l];
        const int en = st + cnt64[l];

        float a0[8] = {0,0,0,0,0,0,0,0};
        float a1[8] = {0,0,0,0,0,0,0,0};
        int k = st;
        for (; k + 3 < en; k += 4) {
            const unsigned w0 = list[k],     w1 = list[k + 1];
            const unsigned w2 = list[k + 2], w3 = list[k + 3];
            const uint4 v0 = *(const uint4*)((const char*)out + (size_t)(w0 & 0x1FFFF) * 512 + sl * 16);
            const uint4 v1 = *(const uint4*)((const char*)out + (size_t)(w1 & 0x1FFFF) * 512 + sl * 16);
            const uint4 v2 = *(const uint4*)((const char*)out + (size_t)(w2 & 0x1FFFF) * 512 + sl * 16);
            const uint4 v3 = *(const uint4*)((const char*)out + (size_t)(w3 & 0x1FFFF) * 512 + sl * 16);
            addrow(a0, v0); addrow(a1, v1); addrow(a0, v2); addrow(a1, v3);
        }
        for (; k < en; ++k) {
            const unsigned w0 = list[k];
            const uint4 v0 = *(const uint4*)((const char*)out + (size_t)(w0 & 0x1FFFF) * 512 + sl * 16);
            addrow(a0, v0);
        }
        #pragma unroll
        for (int q = 0; q < 8; ++q) a0[q] += a1[q];

        const int n = n0 + l;
        if (n < N_NODES) {
            uint4 o;
            o.x = pack_bf16x2(a0[0], a0[1]);
            o.y = pack_bf16x2(a0[2], a0[3]);
            o.z = pack_bf16x2(a0[4], a0[5]);
            o.w = pack_bf16x2(a0[6], a0[7]);
            *(uint4*)((char*)out + (size_t)n * 512 + 256 + sl * 16) = o;
        }
    }
}

#define MT   128

__global__ __launch_bounds__(256) void gcn_gemm_mfma(
    float* __restrict__ out,
    const unsigned short* __restrict__ Wbf,
    const float* __restrict__ b)
{
    __shared__ unsigned short Alds[MT * LDP];
    __shared__ unsigned short Wlds[F * LDP];

    const int tid  = threadIdx.x;
    const int row0 = blockIdx.x * MT;

    #pragma unroll
    for (int i = 0; i < 8; ++i) {
        const int c = tid + i * 256;
        const int r = c >> 4, cc = c & 15;
        *(uint4*)&Wlds[r * LDP + cc * 8] = *(const uint4*)&Wbf[c * 8];
    }
    #pragma unroll
    for (int i = 0; i < 8; ++i) {
        const int c = tid + i * 256;
        const int r = c >> 4, cc = c & 15;
        int gr = row0 + r; if (gr > N_NODES - 1) gr = N_NODES - 1;
        const uint4 v = *(const uint4*)((const char*)out + (size_t)gr * 512 + 256 + cc * 16);
        *(uint4*)&Alds[r * LDP + cc * 8] = v;
    }
    __syncthreads();

    const int lane = tid & 63;
    const int wv   = tid >> 6;
    const int lr   = lane & 15;
    const int lq   = lane >> 4;

    f32x4 acc[2][8] = {};
    #pragma unroll
    for (int kk = 0; kk < 4; ++kk) {
        bf16x8 a[2], w[8];
        #pragma unroll
        for (int i = 0; i < 2; ++i)
            a[i] = __builtin_bit_cast(bf16x8,
                *(const uint4*)&Alds[(wv * 32 + i * 16 + lr) * LDP + kk * 32 + lq * 8]);
        #pragma unroll
        for (int n = 0; n < 8; ++n)
            w[n] = __builtin_bit_cast(bf16x8,
                *(const uint4*)&Wlds[(n * 16 + lr) * LDP + kk * 32 + lq * 8]);
        #pragma unroll
        for (int i = 0; i < 2; ++i)
            #pragma unroll
            for (int n = 0; n < 8; ++n)
                acc[i][n] = __builtin_amdgcn_mfma_f32_16x16x32_bf16(a[i], w[n], acc[i][n], 0, 0, 0);
    }

    float bias[8];
    #pragma unroll
    for (int n = 0; n < 8; ++n) bias[n] = b[n * 16 + lr];

    #pragma unroll
    for (int i = 0; i < 2; ++i) {
        const int rbase = wv * 32 + i * 16 + lq * 4;
        #pragma unroll
        for (int rg = 0; rg < 4; ++rg) {
            const int gr = row0 + rbase + rg;
            if (gr < N_NODES) {
                float* orow = out + (size_t)gr * F;
                #pragma unroll
                for (int n = 0; n < 8; ++n) {
                    const float v = acc[i][n][rg] + bias[n];
                    orow[n * 16 + lr] = v > 0.0f ? v : 0.0f;
                }
            }
        }
    }
}

// ===================== fallback path (ws too small) =========================
__global__ __launch_bounds__(256) void gcn_scatter(
    const float* __restrict__ feat,
    const int* __restrict__ src, const int* __restrict__ dst,
    float* __restrict__ agg)
{
    const int sub  = threadIdx.x >> 5;
    const int lane = threadIdx.x & 31;
    const long long e = (long long)blockIdx.x * 8 + sub;
    if (e >= N_EDGES) return;
    const int s = src[e], d = dst[e];
    const float4 v = *(const float4*)(feat + (size_t)s * F + lane * 4);
    float* ar = agg + (size_t)d * F + lane * 4;
    unsafeAtomicAdd(ar + 0, v.x);
    unsafeAtomicAdd(ar + 1, v.y);
    unsafeAtomicAdd(ar + 2, v.z);
    unsafeAtomicAdd(ar + 3, v.w);
}

#define GR  64
#define LDW 132
__global__ __launch_bounds__(256) void gcn_gemm_relu(
    float* __restrict__ agg_out,
    const float* __restrict__ W, const float* __restrict__ b)
{
    __shared__ float Wl[F][LDW];
    __shared__ float At[GR][LDW];
    const int tid = threadIdx.x;
    const long long row0 = (long long)blockIdx.x * GR;
    #pragma unroll
    for (int i = 0; i < 64; ++i) {
        const int e = tid + i * 256;
        Wl[e >> 7][e & 127] = W[e];
    }
    #pragma unroll
    for (int i = 0; i < 32; ++i) {
        const int e = tid + i * 256;
        const int r = e >> 7, k2 = e & 127;
        const long long gr = row0 + r;
        At[r][k2] = (gr < N_NODES) ? agg_out[gr * F + k2] : 0.0f;
    }
    __syncthreads();
    const int tx = tid & 15, ty = tid >> 4, r0 = ty * 4;
    float acc[4][8];
    #pragma unroll
    for (int r = 0; r < 4; ++r)
        #pragma unroll
        for (int m = 0; m < 8; ++m) acc[r][m] = 0.0f;
    for (int k0 = 0; k0 < F; k0 += 4) {
        float4 a[4], w[8];
        #pragma unroll
        for (int r = 0; r < 4; ++r) a[r] = *(const float4*)&At[r0 + r][k0];
        #pragma unroll
        for (int m = 0; m < 8; ++m) w[m] = *(const float4*)&Wl[tx + 16 * m][k0];
        #pragma unroll
        for (int r = 0; r < 4; ++r)
            #pragma unroll
            for (int m = 0; m < 8; ++m)
                acc[r][m] += a[r].x * w[m].x + a[r].y * w[m].y
                           + a[r].z * w[m].z + a[r].w * w[m].w;
    }
    float bias[8];
    #pragma unroll
    for (int m = 0; m < 8; ++m) bias[m] = b[tx + 16 * m];
    __syncthreads();
    #pragma unroll
    for (int r = 0; r < 4; ++r) {
        const long long gr = row0 + r0 + r;
        if (gr < N_NODES) {
            float* orow = agg_out + gr * F;
            #pragma unroll
            for (int m = 0; m < 8; ++m) {
                const float v = acc[r][m] + bias[m];
                orow[tx + 16 * m] = v > 0.0f ? v : 0.0f;
            }
        }
    }
}

extern "C" void kernel_launch(void* const* d_in, const int* in_sizes, int n_in,
                              void* d_out, int out_size, void* d_ws, size_t ws_size,
                              hipStream_t stream) {
    const float* feat = (const float*)d_in[0];
    const int*   src  = (const int*)d_in[1];
    const int*   dst  = (const int*)d_in[2];
    const float* W    = (const float*)d_in[3];
    const float* b    = (const float*)d_in[4];
    float* out = (float*)d_out;

    // lin path ws: gcur[1600 ints] | bins[NB*CAP uints] | H[N*F bf16] | Wbf[F*F bf16]
    const size_t ws_lin = 1600u * 4 + (size_t)NB * CAP * 4
                        + (size_t)N_NODES * F * 2 + (size_t)F * F * 2;
    // old path: gcur | bins | Wbf
    const size_t ws_old = 1600u * 4 + (size_t)NB * CAP * 4 + (size_t)F * F * 2;

    if (ws_size >= ws_lin) {
        int* gcur = (int*)d_ws;
        unsigned* bins = (unsigned*)(gcur + 1600);
        unsigned short* H = (unsigned short*)(bins + (size_t)NB * CAP);
        unsigned short* Wbf = H + (size_t)N_NODES * F;

        gcn_init     <<<16, 1024, 0, stream>>>(W, Wbf, gcur);
        gcn_bin      <<<BIN_BLOCKS, 1024, 0, stream>>>(src, dst, gcur, bins);
        gcn_hgemm    <<<HGEMM_BLOCKS, 1024, 0, stream>>>(feat, Wbf, H);
        gcn_accum_lin<<<NB, 512, 0, stream>>>(gcur, bins, H, b, out);
    } else if (ws_size >= ws_old) {
        int* gcur = (int*)d_ws;
        unsigned* bins = (unsigned*)(gcur + 1600);
        unsigned short* Wbf = (unsigned short*)(bins + (size_t)NB * CAP);

        hipMemsetAsync(gcur, 0, NB * sizeof(int), stream);
        gcn_front   <<<FRONT_GRID, 1024, 0, stream>>>(feat, W, src, dst, gcur, bins, Wbf, out);
        gcn_accum2  <<<NB, 512, 0, stream>>>(gcur, bins, out);
        gcn_gemm_mfma<<<(N_NODES + MT - 1) / MT, 256, 0, stream>>>(out, Wbf, b);
    } else {
        hipMemsetAsync(out, 0, (size_t)N_NODES * F * sizeof(float), stream);
        gcn_scatter<<<N_EDGES / 8, 256, 0, stream>>>(feat, src, dst, out);
        gcn_gemm_relu<<<(N_NODES + GR - 1) / GR, 256, 0, stream>>>(out, W, b);
    }
}

// Round 6
// 191.876 us; speedup vs baseline: 1.0207x; 1.0138x over previous
//
#include <hip/hip_runtime.h>

#define N_NODES 100000
#define N_EDGES 1600000
#define F 128

#define NB    1563      // buckets of 64 nodes (dst>>6)
#define NBP2  2048      // padded bucket arrays (2/thread at 1024 threads)
#define CAP   1280      // per-bucket capacity: mean 1024, +8 sigma
#define CHUNK 8192      // edges per bin block (run len ~5.2 -> coalesced flush)

#define BIN_BLOCKS   196                 // ceil(1.6M / 8192)
#define HGEMM_BLOCKS 782                 // ceil(100000 / 128)
#define FRONT_GRID_LIN (BIN_BLOCKS + HGEMM_BLOCKS)

#define LDP  136
#define SMEM_BYTES 77824                 // max(bin 77824, hgemm 69632)

typedef __bf16  bf16x8 __attribute__((ext_vector_type(8)));
typedef float   f32x4  __attribute__((ext_vector_type(4)));

__device__ inline unsigned short f32_to_bf16(float f) {
    unsigned u = __builtin_bit_cast(unsigned, f);
    u += 0x7FFFu + ((u >> 16) & 1u);     // RNE, finite inputs
    return (unsigned short)(u >> 16);
}
__device__ inline unsigned pack_bf16x2(float lo, float hi) {
    return (unsigned)f32_to_bf16(lo) | ((unsigned)f32_to_bf16(hi) << 16);
}
__device__ inline void addrow(float* acc, const uint4 v) {
    acc[0] += __builtin_bit_cast(float, v.x << 16);
    acc[1] += __builtin_bit_cast(float, v.x & 0xFFFF0000u);
    acc[2] += __builtin_bit_cast(float, v.y << 16);
    acc[3] += __builtin_bit_cast(float, v.y & 0xFFFF0000u);
    acc[4] += __builtin_bit_cast(float, v.z << 16);
    acc[5] += __builtin_bit_cast(float, v.z & 0xFFFF0000u);
    acc[6] += __builtin_bit_cast(float, v.w << 16);
    acc[7] += __builtin_bit_cast(float, v.w & 0xFFFF0000u);
}

// ============ linear-reordered front: bin edges + H = bf16(feat @ W^T) ======
// blocks [0,196): LDS-staged edge binning (shfl scan).
// blocks [196, 196+782): 128-row MFMA tile of H = feat @ W^T (W converted inline).
__global__ __launch_bounds__(1024) void gcn_front_lin(
    const float* __restrict__ feat, const float* __restrict__ W,
    const int* __restrict__ src, const int* __restrict__ dst,
    int* __restrict__ gcur, unsigned* __restrict__ bins,
    unsigned short* __restrict__ H)
{
    __shared__ __align__(16) unsigned char smem[SMEM_BYTES];

    const int tid = threadIdx.x;
    const int bx  = blockIdx.x;

    if (bx >= BIN_BLOCKS) {
        // ---------------- H-GEMM body (16 waves, 128x128 tile) -------------
        unsigned short* Alds = (unsigned short*)smem;          // 128*LDP bf16
        unsigned short* Wlds = Alds + 128 * LDP;               // 128*LDP bf16
        const int row0 = (bx - BIN_BLOCKS) * 128;

        #pragma unroll
        for (int i = 0; i < 4; ++i) {                          // W f32 -> bf16 LDS (L2-broadcast)
            const int c = tid + i * 1024;                      // float4 index, 4096 exact
            const int r = c >> 5, cc = c & 31;
            const f32x4 v = *(const f32x4*)(W + (size_t)c * 4);
            uint2 p; p.x = pack_bf16x2(v[0], v[1]); p.y = pack_bf16x2(v[2], v[3]);
            *(uint2*)&Wlds[r * LDP + cc * 4] = p;
        }
        #pragma unroll
        for (int i = 0; i < 4; ++i) {                          // feat f32 -> bf16 LDS
            const int c = tid + i * 1024;
            const int r = c >> 5, cc = c & 31;
            int gr = row0 + r; if (gr > N_NODES - 1) gr = N_NODES - 1;
            const f32x4 v = *(const f32x4*)(feat + (size_t)gr * F + cc * 4);
            uint2 p; p.x = pack_bf16x2(v[0], v[1]); p.y = pack_bf16x2(v[2], v[3]);
            *(uint2*)&Alds[r * LDP + cc * 4] = p;
        }
        __syncthreads();

        const int lane = tid & 63, wv = tid >> 6;
        const int lr = lane & 15, lq = lane >> 4;
        const int wr = wv & 7;                                 // row tile (16 rows)
        const int wc = wv >> 3;                                // col half (4 n-tiles)

        f32x4 acc[4] = {};
        #pragma unroll
        for (int kk = 0; kk < 4; ++kk) {
            const bf16x8 a = __builtin_bit_cast(bf16x8,
                *(const uint4*)&Alds[(wr * 16 + lr) * LDP + kk * 32 + lq * 8]);
            #pragma unroll
            for (int n2 = 0; n2 < 4; ++n2) {
                const bf16x8 w = __builtin_bit_cast(bf16x8,
                    *(const uint4*)&Wlds[((wc * 4 + n2) * 16 + lr) * LDP + kk * 32 + lq * 8]);
                acc[n2] = __builtin_amdgcn_mfma_f32_16x16x32_bf16(a, w, acc[n2], 0, 0, 0);
            }
        }
        __syncthreads();                                       // all frag reads done

        // stage output tile into Alds (bf16 row-major), then coalesced copy-out
        #pragma unroll
        for (int rg = 0; rg < 4; ++rg) {
            const int r = wr * 16 + lq * 4 + rg;
            #pragma unroll
            for (int n2 = 0; n2 < 4; ++n2)
                Alds[r * LDP + (wc * 4 + n2) * 16 + lr] = f32_to_bf16(acc[n2][rg]);
        }
        __syncthreads();

        #pragma unroll
        for (int i = 0; i < 2; ++i) {
            const int c = tid + i * 1024;                      // 2048 uint4 = 32KB
            const int r = c >> 4, cc = c & 15;
            const int gr = row0 + r;
            if (gr < N_NODES)
                *(uint4*)(H + (size_t)gr * F + cc * 8) = *(const uint4*)&Alds[r * LDP + cc * 8];
        }
        return;
    }

    // ---------------- bin body ----------------
    unsigned*       cnt    = (unsigned*)smem;                  // NBP2
    unsigned*       off    = cnt + NBP2;                       // NBP2
    int*            gbase  = (int*)(off + NBP2);               // NBP2
    unsigned*       staged = (unsigned*)(gbase + NBP2);        // CHUNK
    unsigned short* sbk    = (unsigned short*)(staged + CHUNK);// CHUNK
    unsigned*       scan   = (unsigned*)(sbk + CHUNK);         // 17 used

    const int e0 = bx * CHUNK;

    #pragma unroll
    for (int i = 0; i < 2; ++i) cnt[tid + i * 1024] = 0;
    __syncthreads();

    int sv[8], dv[8];
    #pragma unroll
    for (int i = 0; i < 8; ++i) {
        const int e = e0 + tid + i * 1024;
        if (e < N_EDGES) {
            sv[i] = src[e];
            dv[i] = dst[e];
            atomicAdd(&cnt[dv[i] >> 6], 1u);
        } else dv[i] = -1;
    }
    __syncthreads();

    // shfl-based scan: wave-inclusive + 16 wave bases (2 barriers)
    const int lane = tid & 63, wid = tid >> 6;
    const unsigned s = cnt[2 * tid] + cnt[2 * tid + 1];
    unsigned v = s;
    #pragma unroll
    for (int o = 1; o < 64; o <<= 1) {
        const unsigned t = __shfl_up(v, o, 64);
        if (lane >= o) v += t;
    }
    if (lane == 63) scan[wid] = v;
    __syncthreads();
    if (tid < 16) {
        const unsigned w = scan[tid];
        unsigned x = w;
        #pragma unroll
        for (int o = 1; o < 16; o <<= 1) {
            const unsigned t = __shfl_up(x, o, 16);
            if (tid >= o) x += t;
        }
        scan[tid] = x - w;            // exclusive wave base
        if (tid == 15) scan[16] = x;  // grand total
    }
    __syncthreads();
    const unsigned incl = v + scan[wid];
    const unsigned run  = incl - s;
    off[2 * tid]     = run;
    off[2 * tid + 1] = run + cnt[2 * tid];
    __syncthreads();

    #pragma unroll
    for (int i = 0; i < 8; ++i) {
        if (dv[i] >= 0) {
            const int bk = dv[i] >> 6;
            const unsigned w = (unsigned)sv[i] | ((unsigned)(dv[i] & 63) << 17);
            const unsigned p = atomicAdd(&off[bk], 1u);
            staged[p] = w;
            sbk[p] = (unsigned short)bk;
        }
    }
    __syncthreads();

    #pragma unroll
    for (int i = 0; i < 2; ++i) {
        const int bk = 2 * tid + i;
        if (bk < NB && cnt[bk] > 0)
            gbase[bk] = atomicAdd(&gcur[bk], (int)cnt[bk]);
    }
    __syncthreads();

    const int c_tot = (int)scan[16];
    for (int p = tid; p < c_tot; p += 1024) {
        const int bk = sbk[p];
        const int gp = gbase[bk] + (p - (int)(off[bk] - cnt[bk]));
        if (gp < CAP) bins[(size_t)bk * CAP + gp] = staged[p];
    }
}

// ============ pass 2: counting-sort + gather of H + bias + ReLU =============
// R1-exact body (static pairing, 8-deep unroll): best measured 66.5 us, VGPR 36.
__global__ __launch_bounds__(512) void gcn_accum_lin(
    const int* __restrict__ gcur,
    const unsigned* __restrict__ bins,
    const unsigned short* __restrict__ H,
    const float* __restrict__ b,
    float* __restrict__ out)
{
    __shared__ unsigned tmp[CAP];
    __shared__ unsigned list[CAP];
    __shared__ int cnt64[64], scn[64], pos64[64], cur64[64];

    const int tid = threadIdx.x;
    const int bkt = blockIdx.x;

    int c = gcur[bkt]; if (c > CAP) c = CAP;
    const unsigned* bb = bins + (size_t)bkt * CAP;

    for (int i = tid; i < c; i += 512) tmp[i] = bb[i];
    if (tid < 64) cnt64[tid] = 0;
    __syncthreads();

    for (int i = tid; i < c; i += 512) atomicAdd(&cnt64[(tmp[i] >> 17) & 63], 1);
    __syncthreads();

    if (tid < 64) scn[tid] = cnt64[tid];
    __syncthreads();
    #pragma unroll
    for (int o = 1; o < 64; o <<= 1) {
        int t = 0;
        if (tid < 64 && tid >= o) t = scn[tid - o];
        __syncthreads();
        if (tid < 64) scn[tid] += t;
        __syncthreads();
    }
    if (tid < 64) {
        const int st = scn[tid] - cnt64[tid];
        pos64[tid] = st;
        cur64[tid] = st;
    }
    __syncthreads();

    for (int i = tid; i < c; i += 512) {
        const unsigned w = tmp[i];
        const int p = atomicAdd(&cur64[(w >> 17) & 63], 1);
        list[p] = w;
    }
    __syncthreads();

    const int grp = tid >> 4;        // 0..31
    const int sl  = tid & 15;        // feats [8*sl, 8*sl+8)
    const int n0  = bkt * 64;

    #pragma unroll
    for (int ni = 0; ni < 2; ++ni) {
        const int l  = grp * 2 + ni;
        const int st = pos64[l];
        const int en = st + cnt64[l];

        float a0[8] = {0,0,0,0,0,0,0,0};
        float a1[8] = {0,0,0,0,0,0,0,0};
        int k = st;
        for (; k + 7 < en; k += 8) {             // 8 loads in flight
            const unsigned w0 = list[k],     w1 = list[k + 1];
            const unsigned w2 = list[k + 2], w3 = list[k + 3];
            const unsigned w4 = list[k + 4], w5 = list[k + 5];
            const unsigned w6 = list[k + 6], w7 = list[k + 7];
            const uint4 v0 = *(const uint4*)(H + (size_t)(w0 & 0x1FFFF) * F + sl * 8);
            const uint4 v1 = *(const uint4*)(H + (size_t)(w1 & 0x1FFFF) * F + sl * 8);
            const uint4 v2 = *(const uint4*)(H + (size_t)(w2 & 0x1FFFF) * F + sl * 8);
            const uint4 v3 = *(const uint4*)(H + (size_t)(w3 & 0x1FFFF) * F + sl * 8);
            const uint4 v4 = *(const uint4*)(H + (size_t)(w4 & 0x1FFFF) * F + sl * 8);
            const uint4 v5 = *(const uint4*)(H + (size_t)(w5 & 0x1FFFF) * F + sl * 8);
            const uint4 v6 = *(const uint4*)(H + (size_t)(w6 & 0x1FFFF) * F + sl * 8);
            const uint4 v7 = *(const uint4*)(H + (size_t)(w7 & 0x1FFFF) * F + sl * 8);
            addrow(a0, v0); addrow(a1, v1); addrow(a0, v2); addrow(a1, v3);
            addrow(a0, v4); addrow(a1, v5); addrow(a0, v6); addrow(a1, v7);
        }
        for (; k + 3 < en; k += 4) {
            const unsigned w0 = list[k],     w1 = list[k + 1];
            const unsigned w2 = list[k + 2], w3 = list[k + 3];
            const uint4 v0 = *(const uint4*)(H + (size_t)(w0 & 0x1FFFF) * F + sl * 8);
            const uint4 v1 = *(const uint4*)(H + (size_t)(w1 & 0x1FFFF) * F + sl * 8);
            const uint4 v2 = *(const uint4*)(H + (size_t)(w2 & 0x1FFFF) * F + sl * 8);
            const uint4 v3 = *(const uint4*)(H + (size_t)(w3 & 0x1FFFF) * F + sl * 8);
            addrow(a0, v0); addrow(a1, v1); addrow(a0, v2); addrow(a1, v3);
        }
        for (; k < en; ++k) {
            const unsigned w0 = list[k];
            const uint4 v0 = *(const uint4*)(H + (size_t)(w0 & 0x1FFFF) * F + sl * 8);
            addrow(a0, v0);
        }
        #pragma unroll
        for (int q = 0; q < 8; ++q) a0[q] += a1[q];

        const int n = n0 + l;
        if (n < N_NODES) {
            const float4 b0 = *(const float4*)(b + sl * 8);
            const float4 b1 = *(const float4*)(b + sl * 8 + 4);
            float4 o0, o1;
            o0.x = fmaxf(a0[0] + b0.x, 0.0f);
            o0.y = fmaxf(a0[1] + b0.y, 0.0f);
            o0.z = fmaxf(a0[2] + b0.z, 0.0f);
            o0.w = fmaxf(a0[3] + b0.w, 0.0f);
            o1.x = fmaxf(a0[4] + b1.x, 0.0f);
            o1.y = fmaxf(a0[5] + b1.y, 0.0f);
            o1.z = fmaxf(a0[6] + b1.z, 0.0f);
            o1.w = fmaxf(a0[7] + b1.w, 0.0f);
            float* orow = out + (size_t)n * F + sl * 8;
            *(float4*)orow = o0;
            *(float4*)(orow + 4) = o1;
        }
    }
}

// ===================== old 3-kernel path (ws mid-size fallback) =============
#define FEAT_BLOCKS 3125
#define WCONV_BLOCKS 16
#define FRONT_GRID  (BIN_BLOCKS + FEAT_BLOCKS + WCONV_BLOCKS)

__global__ __launch_bounds__(1024) void gcn_front(
    const float* __restrict__ feat, const float* __restrict__ W,
    const int* __restrict__ src, const int* __restrict__ dst,
    int* __restrict__ gcur, unsigned* __restrict__ bins,
    unsigned short* __restrict__ Wbf, float* __restrict__ out)
{
    __shared__ unsigned cnt[NBP2];
    __shared__ unsigned off[NBP2];
    __shared__ int      gbase[NBP2];
    __shared__ unsigned staged[CHUNK];
    __shared__ unsigned short sbk[CHUNK];
    __shared__ unsigned scan[1024];

    const int tid = threadIdx.x;
    const int bx  = blockIdx.x;

    if (bx >= BIN_BLOCKS) {
        const int rb = bx - BIN_BLOCKS;
        if (rb < FEAT_BLOCKS) {
            const int t = rb * 1024 + tid;
            const float4 v = *(const float4*)(feat + (size_t)t * 4);
            uint2 p;
            p.x = pack_bf16x2(v.x, v.y);
            p.y = pack_bf16x2(v.z, v.w);
            const int n = t >> 5, q = t & 31;
            *(uint2*)((char*)out + (size_t)n * 512 + q * 8) = p;
        } else {
            const int i = (rb - FEAT_BLOCKS) * 1024 + tid;
            Wbf[i] = f32_to_bf16(W[i]);
        }
        return;
    }

    const int e0 = bx * CHUNK;

    #pragma unroll
    for (int i = 0; i < 2; ++i) cnt[tid + i * 1024] = 0;
    __syncthreads();

    int sv[8], dv[8];
    #pragma unroll
    for (int i = 0; i < 8; ++i) {
        const int e = e0 + tid + i * 1024;
        if (e < N_EDGES) {
            sv[i] = src[e];
            dv[i] = dst[e];
            atomicAdd(&cnt[dv[i] >> 6], 1u);
        } else dv[i] = -1;
    }
    __syncthreads();

    const unsigned s = cnt[2 * tid] + cnt[2 * tid + 1];
    scan[tid] = s;
    __syncthreads();
    for (int o = 1; o < 1024; o <<= 1) {
        const unsigned t = (tid >= o) ? scan[tid - o] : 0;
        __syncthreads();
        scan[tid] += t;
        __syncthreads();
    }
    const unsigned run = scan[tid] - s;
    off[2 * tid]     = run;
    off[2 * tid + 1] = run + cnt[2 * tid];
    __syncthreads();

    #pragma unroll
    for (int i = 0; i < 8; ++i) {
        if (dv[i] >= 0) {
            const int bk = dv[i] >> 6;
            const unsigned w = (unsigned)sv[i] | ((unsigned)(dv[i] & 63) << 17);
            const unsigned p = atomicAdd(&off[bk], 1u);
            staged[p] = w;
            sbk[p] = (unsigned short)bk;
        }
    }
    __syncthreads();

    #pragma unroll
    for (int i = 0; i < 2; ++i) {
        const int bk = 2 * tid + i;
        if (bk < NB && cnt[bk] > 0)
            gbase[bk] = atomicAdd(&gcur[bk], (int)cnt[bk]);
    }
    __syncthreads();

    const int c_tot = (int)scan[1023];
    for (int p = tid; p < c_tot; p += 1024) {
        const int bk = sbk[p];
        const int gp = gbase[bk] + (p - (int)(off[bk] - cnt[bk]));
        if (gp < CAP) bins[(size_t)bk * CAP + gp] = staged[p];
    }
}

__global__ __launch_bounds__(512) void gcn_accum2(
    const int* __restrict__ gcur,
    const unsigned* __restrict__ bins,
    float* __restrict__ out)
{
    __shared__ unsigned tmp[CAP];
    __shared__ unsigned list[CAP];
    __shared__ int cnt64[64], scn[64], pos64[64], cur64[64];

    const int tid = threadIdx.x;
    const int bkt = blockIdx.x;

    int c = gcur[bkt]; if (c > CAP) c = CAP;
    const unsigned* bb = bins + (size_t)bkt * CAP;

    for (int i = tid; i < c; i += 512) tmp[i] = bb[i];
    if (tid < 64) cnt64[tid] = 0;
    __syncthreads();

    for (int i = tid; i < c; i += 512) atomicAdd(&cnt64[(tmp[i] >> 17) & 63], 1);
    __syncthreads();

    if (tid < 64) scn[tid] = cnt64[tid];
    __syncthreads();
    #pragma unroll
    for (int o = 1; o < 64; o <<= 1) {
        int t = 0;
        if (tid < 64 && tid >= o) t = scn[tid - o];
        __syncthreads();
        if (tid < 64) scn[tid] += t;
        __syncthreads();
    }
    if (tid < 64) {
        const int st = scn[tid] - cnt64[tid];
        pos64[tid] = st;
        cur64[tid] = st;
    }
    __syncthreads();

    for (int i = tid; i < c; i += 512) {
        const unsigned w = tmp[i];
        const int p = atomicAdd(&cur64[(w >> 17) & 63], 1);
        list[p] = w;
    }
    __syncthreads();

    const int grp = tid >> 4;
    const int sl  = tid & 15;
    const int n0  = bkt * 64;

    #pragma unroll
    for (int ni = 0; ni < 2; ++ni) {
        const int l  = grp * 2 + ni;
        const int st = pos64[l];
        const int en = st + cnt64[l];

        float a0[8] = {0,0,0,0,0,0,0,0};
        float a1[8] = {0,0,0,0,0,0,0,0};
        int k = st;
        for (; k + 3 < en; k += 4) {
            const unsigned w0 = list[k],     w1 = list[k + 1];
            const unsigned w2 = list[k + 2], w3 = list[k + 3];
            const uint4 v0 = *(const uint4*)((const char*)out + (size_t)(w0 & 0x1FFFF) * 512 + sl * 16);
            const uint4 v1 = *(const uint4*)((const char*)out + (size_t)(w1 & 0x1FFFF) * 512 + sl * 16);
            const uint4 v2 = *(const uint4*)((const char*)out + (size_t)(w2 & 0x1FFFF) * 512 + sl * 16);
            const uint4 v3 = *(const uint4*)((const char*)out + (size_t)(w3 & 0x1FFFF) * 512 + sl * 16);
            addrow(a0, v0); addrow(a1, v1); addrow(a0, v2); addrow(a1, v3);
        }
        for (; k < en; ++k) {
            const unsigned w0 = list[k];
            const uint4 v0 = *(const uint4*)((const char*)out + (size_t)(w0 & 0x1FFFF) * 512 + sl * 16);
            addrow(a0, v0);
        }
        #pragma unroll
        for (int q = 0; q < 8; ++q) a0[q] += a1[q];

        const int n = n0 + l;
        if (n < N_NODES) {
            uint4 o;
            o.x = pack_bf16x2(a0[0], a0[1]);
            o.y = pack_bf16x2(a0[2], a0[3]);
            o.z = pack_bf16x2(a0[4], a0[5]);
            o.w = pack_bf16x2(a0[6], a0[7]);
            *(uint4*)((char*)out + (size_t)n * 512 + 256 + sl * 16) = o;
        }
    }
}

#define MT   128

__global__ __launch_bounds__(256) void gcn_gemm_mfma(
    float* __restrict__ out,
    const unsigned short* __restrict__ Wbf,
    const float* __restrict__ b)
{
    __shared__ unsigned short Alds[MT * LDP];
    __shared__ unsigned short Wlds[F * LDP];

    const int tid  = threadIdx.x;
    const int row0 = blockIdx.x * MT;

    #pragma unroll
    for (int i = 0; i < 8; ++i) {
        const int c = tid + i * 256;
        const int r = c >> 4, cc = c & 15;
        *(uint4*)&Wlds[r * LDP + cc * 8] = *(const uint4*)&Wbf[c * 8];
    }
    #pragma unroll
    for (int i = 0; i < 8; ++i) {
        const int c = tid + i * 256;
        const int r = c >> 4, cc = c & 15;
        int gr = row0 + r; if (gr > N_NODES - 1) gr = N_NODES - 1;
        const uint4 v = *(const uint4*)((const char*)out + (size_t)gr * 512 + 256 + cc * 16);
        *(uint4*)&Alds[r * LDP + cc * 8] = v;
    }
    __syncthreads();

    const int lane = tid & 63;
    const int wv   = tid >> 6;
    const int lr   = lane & 15;
    const int lq   = lane >> 4;

    f32x4 acc[2][8] = {};
    #pragma unroll
    for (int kk = 0; kk < 4; ++kk) {
        bf16x8 a[2], w[8];
        #pragma unroll
        for (int i = 0; i < 2; ++i)
            a[i] = __builtin_bit_cast(bf16x8,
                *(const uint4*)&Alds[(wv * 32 + i * 16 + lr) * LDP + kk * 32 + lq * 8]);
        #pragma unroll
        for (int n = 0; n < 8; ++n)
            w[n] = __builtin_bit_cast(bf16x8,
                *(const uint4*)&Wlds[(n * 16 + lr) * LDP + kk * 32 + lq * 8]);
        #pragma unroll
        for (int i = 0; i < 2; ++i)
            #pragma unroll
            for (int n = 0; n < 8; ++n)
                acc[i][n] = __builtin_amdgcn_mfma_f32_16x16x32_bf16(a[i], w[n], acc[i][n], 0, 0, 0);
    }

    float bias[8];
    #pragma unroll
    for (int n = 0; n < 8; ++n) bias[n] = b[n * 16 + lr];

    #pragma unroll
    for (int i = 0; i < 2; ++i) {
        const int rbase = wv * 32 + i * 16 + lq * 4;
        #pragma unroll
        for (int rg = 0; rg < 4; ++rg) {
            const int gr = row0 + rbase + rg;
            if (gr < N_NODES) {
                float* orow = out + (size_t)gr * F;
                #pragma unroll
                for (int n = 0; n < 8; ++n) {
                    const float v = acc[i][n][rg] + bias[n];
                    orow[n * 16 + lr] = v > 0.0f ? v : 0.0f;
                }
            }
        }
    }
}

// ===================== fallback path (ws too small) =========================
__global__ __launch_bounds__(256) void gcn_scatter(
    const float* __restrict__ feat,
    const int* __restrict__ src, const int* __restrict__ dst,
    float* __restrict__ agg)
{
    const int sub  = threadIdx.x >> 5;
    const int lane = threadIdx.x & 31;
    const long long e = (long long)blockIdx.x * 8 + sub;
    if (e >= N_EDGES) return;
    const int s = src[e], d = dst[e];
    const float4 v = *(const float4*)(feat + (size_t)s * F + lane * 4);
    float* ar = agg + (size_t)d * F + lane * 4;
    unsafeAtomicAdd(ar + 0, v.x);
    unsafeAtomicAdd(ar + 1, v.y);
    unsafeAtomicAdd(ar + 2, v.z);
    unsafeAtomicAdd(ar + 3, v.w);
}

#define GR  64
#define LDW 132
__global__ __launch_bounds__(256) void gcn_gemm_relu(
    float* __restrict__ agg_out,
    const float* __restrict__ W, const float* __restrict__ b)
{
    __shared__ float Wl[F][LDW];
    __shared__ float At[GR][LDW];
    const int tid = threadIdx.x;
    const long long row0 = (long long)blockIdx.x * GR;
    #pragma unroll
    for (int i = 0; i < 64; ++i) {
        const int e = tid + i * 256;
        Wl[e >> 7][e & 127] = W[e];
    }
    #pragma unroll
    for (int i = 0; i < 32; ++i) {
        const int e = tid + i * 256;
        const int r = e >> 7, k2 = e & 127;
        const long long gr = row0 + r;
        At[r][k2] = (gr < N_NODES) ? agg_out[gr * F + k2] : 0.0f;
    }
    __syncthreads();
    const int tx = tid & 15, ty = tid >> 4, r0 = ty * 4;
    float acc[4][8];
    #pragma unroll
    for (int r = 0; r < 4; ++r)
        #pragma unroll
        for (int m = 0; m < 8; ++m) acc[r][m] = 0.0f;
    for (int k0 = 0; k0 < F; k0 += 4) {
        float4 a[4], w[8];
        #pragma unroll
        for (int r = 0; r < 4; ++r) a[r] = *(const float4*)&At[r0 + r][k0];
        #pragma unroll
        for (int m = 0; m < 8; ++m) w[m] = *(const float4*)&Wl[tx + 16 * m][k0];
        #pragma unroll
        for (int r = 0; r < 4; ++r)
            #pragma unroll
            for (int m = 0; m < 8; ++m)
                acc[r][m] += a[r].x * w[m].x + a[r].y * w[m].y
                           + a[r].z * w[m].z + a[r].w * w[m].w;
    }
    float bias[8];
    #pragma unroll
    for (int m = 0; m < 8; ++m) bias[m] = b[tx + 16 * m];
    __syncthreads();
    #pragma unroll
    for (int r = 0; r < 4; ++r) {
        const long long gr = row0 + r0 + r;
        if (gr < N_NODES) {
            float* orow = agg_out + gr * F;
            #pragma unroll
            for (int m = 0; m < 8; ++m) {
                const float v = acc[r][m] + bias[m];
                orow[tx + 16 * m] = v > 0.0f ? v : 0.0f;
            }
        }
    }
}

extern "C" void kernel_launch(void* const* d_in, const int* in_sizes, int n_in,
                              void* d_out, int out_size, void* d_ws, size_t ws_size,
                              hipStream_t stream) {
    const float* feat = (const float*)d_in[0];
    const int*   src  = (const int*)d_in[1];
    const int*   dst  = (const int*)d_in[2];
    const float* W    = (const float*)d_in[3];
    const float* b    = (const float*)d_in[4];
    float* out = (float*)d_out;

    // lin path ws: gcur[1600 ints] | bins[NB*CAP uints] | H[N*F bf16]
    const size_t ws_lin = 1600u * 4 + (size_t)NB * CAP * 4 + (size_t)N_NODES * F * 2;
    // old path: gcur | bins | Wbf
    const size_t ws_old = 1600u * 4 + (size_t)NB * CAP * 4 + (size_t)F * F * 2;

    if (ws_size >= ws_lin) {
        int* gcur = (int*)d_ws;
        unsigned* bins = (unsigned*)(gcur + 1600);
        unsigned short* H = (unsigned short*)(bins + (size_t)NB * CAP);

        hipMemsetAsync(gcur, 0, NB * sizeof(int), stream);
        gcn_front_lin<<<FRONT_GRID_LIN, 1024, 0, stream>>>(feat, W, src, dst, gcur, bins, H);
        gcn_accum_lin<<<NB, 512, 0, stream>>>(gcur, bins, H, b, out);
    } else if (ws_size >= ws_old) {
        int* gcur = (int*)d_ws;
        unsigned* bins = (unsigned*)(gcur + 1600);
        unsigned short* Wbf = (unsigned short*)(bins + (size_t)NB * CAP);

        hipMemsetAsync(gcur, 0, NB * sizeof(int), stream);
        gcn_front   <<<FRONT_GRID, 1024, 0, stream>>>(feat, W, src, dst, gcur, bins, Wbf, out);
        gcn_accum2  <<<NB, 512, 0, stream>>>(gcur, bins, out);
        gcn_gemm_mfma<<<(N_NODES + MT - 1) / MT, 256, 0, stream>>>(out, Wbf, b);
    } else {
        hipMemsetAsync(out, 0, (size_t)N_NODES * F * sizeof(float), stream);
        gcn_scatter<<<N_EDGES / 8, 256, 0, stream>>>(feat, src, dst, out);
        gcn_gemm_relu<<<(N_NODES + GR - 1) / GR, 256, 0, stream>>>(out, W, b);
    }
}

// Round 7
// 182.305 us; speedup vs baseline: 1.0743x; 1.0525x over previous
//
#include <hip/hip_runtime.h>

#define N_NODES 100000
#define N_EDGES 1600000
#define F 128

// ---- old-path constants (fallbacks) ----
#define NB    1563      // buckets of 64 nodes (dst>>6)
#define NBP2  2048
#define CAP   1280
#define CHUNK 8192      // edges per bin block

// ---- lin-path constants: one bucket per resident block slot ----
#define NB2   1021      // buckets of 98 nodes (dst/98); 1021 <= 1024 slots -> 1 round
#define NPB   98        // nodes per bucket
#define CAP2  1920      // mean 1568, +8.9 sigma

#define BIN_BLOCKS   196                 // ceil(1.6M / 8192)
#define HGEMM_BLOCKS 782                 // ceil(100000 / 128)
#define FRONT_GRID_LIN (BIN_BLOCKS + HGEMM_BLOCKS)

#define LDP  136
#define SMEM_BYTES 69632                 // max(hgemm 69632, bin 61600)

typedef __bf16  bf16x8 __attribute__((ext_vector_type(8)));
typedef float   f32x4  __attribute__((ext_vector_type(4)));

__device__ inline unsigned short f32_to_bf16(float f) {
    unsigned u = __builtin_bit_cast(unsigned, f);
    u += 0x7FFFu + ((u >> 16) & 1u);     // RNE, finite inputs
    return (unsigned short)(u >> 16);
}
__device__ inline unsigned pack_bf16x2(float lo, float hi) {
    return (unsigned)f32_to_bf16(lo) | ((unsigned)f32_to_bf16(hi) << 16);
}
__device__ inline void addrow(float* acc, const uint4 v) {
    acc[0] += __builtin_bit_cast(float, v.x << 16);
    acc[1] += __builtin_bit_cast(float, v.x & 0xFFFF0000u);
    acc[2] += __builtin_bit_cast(float, v.y << 16);
    acc[3] += __builtin_bit_cast(float, v.y & 0xFFFF0000u);
    acc[4] += __builtin_bit_cast(float, v.z << 16);
    acc[5] += __builtin_bit_cast(float, v.z & 0xFFFF0000u);
    acc[6] += __builtin_bit_cast(float, v.w << 16);
    acc[7] += __builtin_bit_cast(float, v.w & 0xFFFF0000u);
}

// ============ linear-reordered front: bin edges + H = bf16(feat @ W^T) ======
// blocks [0,196): LDS-staged edge binning into 1021 buckets of 98 nodes.
// blocks [196, 196+782): 128-row MFMA tile of H = feat @ W^T (W converted inline).
__global__ __launch_bounds__(1024) void gcn_front_lin(
    const float* __restrict__ feat, const float* __restrict__ W,
    const int* __restrict__ src, const int* __restrict__ dst,
    int* __restrict__ gcur, unsigned* __restrict__ bins,
    unsigned short* __restrict__ H)
{
    __shared__ __align__(16) unsigned char smem[SMEM_BYTES];

    const int tid = threadIdx.x;
    const int bx  = blockIdx.x;

    if (bx >= BIN_BLOCKS) {
        // ---------------- H-GEMM body (16 waves, 128x128 tile) -------------
        unsigned short* Alds = (unsigned short*)smem;          // 128*LDP bf16
        unsigned short* Wlds = Alds + 128 * LDP;               // 128*LDP bf16
        const int row0 = (bx - BIN_BLOCKS) * 128;

        #pragma unroll
        for (int i = 0; i < 4; ++i) {                          // W f32 -> bf16 LDS (L2-broadcast)
            const int c = tid + i * 1024;                      // float4 index, 4096 exact
            const int r = c >> 5, cc = c & 31;
            const f32x4 v = *(const f32x4*)(W + (size_t)c * 4);
            uint2 p; p.x = pack_bf16x2(v[0], v[1]); p.y = pack_bf16x2(v[2], v[3]);
            *(uint2*)&Wlds[r * LDP + cc * 4] = p;
        }
        #pragma unroll
        for (int i = 0; i < 4; ++i) {                          // feat f32 -> bf16 LDS
            const int c = tid + i * 1024;
            const int r = c >> 5, cc = c & 31;
            int gr = row0 + r; if (gr > N_NODES - 1) gr = N_NODES - 1;
            const f32x4 v = *(const f32x4*)(feat + (size_t)gr * F + cc * 4);
            uint2 p; p.x = pack_bf16x2(v[0], v[1]); p.y = pack_bf16x2(v[2], v[3]);
            *(uint2*)&Alds[r * LDP + cc * 4] = p;
        }
        __syncthreads();

        const int lane = tid & 63, wv = tid >> 6;
        const int lr = lane & 15, lq = lane >> 4;
        const int wr = wv & 7;                                 // row tile (16 rows)
        const int wc = wv >> 3;                                // col half (4 n-tiles)

        f32x4 acc[4] = {};
        #pragma unroll
        for (int kk = 0; kk < 4; ++kk) {
            const bf16x8 a = __builtin_bit_cast(bf16x8,
                *(const uint4*)&Alds[(wr * 16 + lr) * LDP + kk * 32 + lq * 8]);
            #pragma unroll
            for (int n2 = 0; n2 < 4; ++n2) {
                const bf16x8 w = __builtin_bit_cast(bf16x8,
                    *(const uint4*)&Wlds[((wc * 4 + n2) * 16 + lr) * LDP + kk * 32 + lq * 8]);
                acc[n2] = __builtin_amdgcn_mfma_f32_16x16x32_bf16(a, w, acc[n2], 0, 0, 0);
            }
        }
        __syncthreads();                                       // all frag reads done

        // stage output tile into Alds (bf16 row-major), then coalesced copy-out
        #pragma unroll
        for (int rg = 0; rg < 4; ++rg) {
            const int r = wr * 16 + lq * 4 + rg;
            #pragma unroll
            for (int n2 = 0; n2 < 4; ++n2)
                Alds[r * LDP + (wc * 4 + n2) * 16 + lr] = f32_to_bf16(acc[n2][rg]);
        }
        __syncthreads();

        #pragma unroll
        for (int i = 0; i < 2; ++i) {
            const int c = tid + i * 1024;                      // 2048 uint4 = 32KB
            const int r = c >> 4, cc = c & 15;
            const int gr = row0 + r;
            if (gr < N_NODES)
                *(uint4*)(H + (size_t)gr * F + cc * 8) = *(const uint4*)&Alds[r * LDP + cc * 8];
        }
        return;
    }

    // ---------------- bin body: 1 bucket per thread in count/scan ----------
    unsigned*       cnt    = (unsigned*)smem;                  // 1024
    unsigned*       off    = cnt + 1024;                       // 1024
    int*            gbase  = (int*)(off + 1024);               // 1024
    unsigned*       staged = (unsigned*)(gbase + 1024);        // CHUNK
    unsigned short* sbk    = (unsigned short*)(staged + CHUNK);// CHUNK
    unsigned*       scan   = (unsigned*)(sbk + CHUNK);         // 17 used

    const int e0 = bx * CHUNK;

    cnt[tid] = 0;
    __syncthreads();

    int bkv[8]; unsigned wv8[8];
    #pragma unroll
    for (int i = 0; i < 8; ++i) {
        const int e = e0 + tid + i * 1024;
        if (e < N_EDGES) {
            const int s = src[e];
            const int d = dst[e];
            const int bk  = d / NPB;                 // magic-mul division
            const int idx = d - bk * NPB;            // 0..97
            wv8[i] = (unsigned)s | ((unsigned)idx << 17);
            bkv[i] = bk;
            atomicAdd(&cnt[bk], 1u);
        } else bkv[i] = -1;
    }
    __syncthreads();

    // shfl-based scan over 1024 buckets: wave-inclusive + 16 wave bases
    const int lane = tid & 63, wid = tid >> 6;
    const unsigned s = cnt[tid];
    unsigned v = s;
    #pragma unroll
    for (int o = 1; o < 64; o <<= 1) {
        const unsigned t = __shfl_up(v, o, 64);
        if (lane >= o) v += t;
    }
    if (lane == 63) scan[wid] = v;
    __syncthreads();
    if (tid < 16) {
        const unsigned w = scan[tid];
        unsigned x = w;
        #pragma unroll
        for (int o = 1; o < 16; o <<= 1) {
            const unsigned t = __shfl_up(x, o, 16);
            if (tid >= o) x += t;
        }
        scan[tid] = x - w;            // exclusive wave base
        if (tid == 15) scan[16] = x;  // grand total
    }
    __syncthreads();
    const unsigned run = v + scan[wid] - s;          // exclusive prefix for bucket tid
    off[tid] = run;
    __syncthreads();

    #pragma unroll
    for (int i = 0; i < 8; ++i) {
        if (bkv[i] >= 0) {
            const unsigned p = atomicAdd(&off[bkv[i]], 1u);
            staged[p] = wv8[i];
            sbk[p] = (unsigned short)bkv[i];
        }
    }
    __syncthreads();

    if (tid < NB2 && cnt[tid] > 0)
        gbase[tid] = atomicAdd(&gcur[tid], (int)cnt[tid]);
    __syncthreads();

    const int c_tot = (int)scan[16];
    for (int p = tid; p < c_tot; p += 1024) {
        const int bk = sbk[p];
        const int gp = gbase[bk] + (p - (int)(off[bk] - cnt[bk]));
        if (gp < CAP2) bins[(size_t)bk * CAP2 + gp] = staged[p];
    }
}

// ============ pass 2: counting-sort + gather of H + bias + ReLU =============
// 1021 blocks == one full residency round (4 blocks/CU x 256 CU = 1024 slots).
__global__ __launch_bounds__(512) void gcn_accum_lin(
    const int* __restrict__ gcur,
    const unsigned* __restrict__ bins,
    const unsigned short* __restrict__ H,
    const float* __restrict__ b,
    float* __restrict__ out)
{
    __shared__ unsigned tmp[CAP2];
    __shared__ unsigned list[CAP2];
    __shared__ int cnt128[128], scn[128], pos128[128], cur128[128];
    __shared__ int nextn;

    const int tid  = threadIdx.x;
    const int bkt  = blockIdx.x;
    const int lane = tid & 63;
    const int sl   = tid & 15;       // feats [8*sl, 8*sl+8)

    int c = gcur[bkt]; if (c > CAP2) c = CAP2;
    const unsigned* bb = bins + (size_t)bkt * CAP2;

    for (int i = tid; i < c; i += 512) tmp[i] = bb[i];
    if (tid < 128) cnt128[tid] = 0;
    if (tid == 0) nextn = 0;
    __syncthreads();

    for (int i = tid; i < c; i += 512) atomicAdd(&cnt128[(tmp[i] >> 17) & 127], 1);
    __syncthreads();

    // 2-wave shfl scan over 128 entries
    if (tid < 128) {
        const int cv = cnt128[tid];
        int x = cv;
        #pragma unroll
        for (int o = 1; o < 64; o <<= 1) {
            const int t = __shfl_up(x, o, 64);
            if ((tid & 63) >= o) x += t;
        }
        scn[tid] = x;                 // inclusive within each 64-wave
    }
    __syncthreads();
    if (tid < 128) {
        const int base = (tid >= 64) ? scn[63] : 0;
        const int st = scn[tid] + base - cnt128[tid];
        pos128[tid] = st;
        cur128[tid] = st;
    }
    __syncthreads();

    for (int i = tid; i < c; i += 512) {
        const unsigned w = tmp[i];
        const int p = atomicAdd(&cur128[(w >> 17) & 127], 1);
        list[p] = w;
    }
    __syncthreads();

    const int n0 = bkt * NPB;

    const float4 b0 = *(const float4*)(b + sl * 8);
    const float4 b1 = *(const float4*)(b + sl * 8 + 4);

    // dynamic node assignment: 16-lane groups grab node slots greedily
    for (;;) {
        int myn = 0;
        if (sl == 0) myn = atomicAdd(&nextn, 1);
        myn = __shfl(myn, lane & 48, 64);
        if (myn >= NPB) break;

        const int st = pos128[myn];
        const int en = st + cnt128[myn];

        float a0[8] = {0,0,0,0,0,0,0,0};
        float a1[8] = {0,0,0,0,0,0,0,0};
        int k = st;
        for (; k + 7 < en; k += 8) {             // 8 loads in flight
            const unsigned w0 = list[k],     w1 = list[k + 1];
            const unsigned w2 = list[k + 2], w3 = list[k + 3];
            const unsigned w4 = list[k + 4], w5 = list[k + 5];
            const unsigned w6 = list[k + 6], w7 = list[k + 7];
            const uint4 v0 = *(const uint4*)(H + (size_t)(w0 & 0x1FFFF) * F + sl * 8);
            const uint4 v1 = *(const uint4*)(H + (size_t)(w1 & 0x1FFFF) * F + sl * 8);
            const uint4 v2 = *(const uint4*)(H + (size_t)(w2 & 0x1FFFF) * F + sl * 8);
            const uint4 v3 = *(const uint4*)(H + (size_t)(w3 & 0x1FFFF) * F + sl * 8);
            const uint4 v4 = *(const uint4*)(H + (size_t)(w4 & 0x1FFFF) * F + sl * 8);
            const uint4 v5 = *(const uint4*)(H + (size_t)(w5 & 0x1FFFF) * F + sl * 8);
            const uint4 v6 = *(const uint4*)(H + (size_t)(w6 & 0x1FFFF) * F + sl * 8);
            const uint4 v7 = *(const uint4*)(H + (size_t)(w7 & 0x1FFFF) * F + sl * 8);
            addrow(a0, v0); addrow(a1, v1); addrow(a0, v2); addrow(a1, v3);
            addrow(a0, v4); addrow(a1, v5); addrow(a0, v6); addrow(a1, v7);
        }
        for (; k + 3 < en; k += 4) {
            const unsigned w0 = list[k],     w1 = list[k + 1];
            const unsigned w2 = list[k + 2], w3 = list[k + 3];
            const uint4 v0 = *(const uint4*)(H + (size_t)(w0 & 0x1FFFF) * F + sl * 8);
            const uint4 v1 = *(const uint4*)(H + (size_t)(w1 & 0x1FFFF) * F + sl * 8);
            const uint4 v2 = *(const uint4*)(H + (size_t)(w2 & 0x1FFFF) * F + sl * 8);
            const uint4 v3 = *(const uint4*)(H + (size_t)(w3 & 0x1FFFF) * F + sl * 8);
            addrow(a0, v0); addrow(a1, v1); addrow(a0, v2); addrow(a1, v3);
        }
        for (; k < en; ++k) {
            const unsigned w0 = list[k];
            const uint4 v0 = *(const uint4*)(H + (size_t)(w0 & 0x1FFFF) * F + sl * 8);
            addrow(a0, v0);
        }
        #pragma unroll
        for (int q = 0; q < 8; ++q) a0[q] += a1[q];

        const int n = n0 + myn;
        if (n < N_NODES) {
            float4 o0, o1;
            o0.x = fmaxf(a0[0] + b0.x, 0.0f);
            o0.y = fmaxf(a0[1] + b0.y, 0.0f);
            o0.z = fmaxf(a0[2] + b0.z, 0.0f);
            o0.w = fmaxf(a0[3] + b0.w, 0.0f);
            o1.x = fmaxf(a0[4] + b1.x, 0.0f);
            o1.y = fmaxf(a0[5] + b1.y, 0.0f);
            o1.z = fmaxf(a0[6] + b1.z, 0.0f);
            o1.w = fmaxf(a0[7] + b1.w, 0.0f);
            float* orow = out + (size_t)n * F + sl * 8;
            *(float4*)orow = o0;
            *(float4*)(orow + 4) = o1;
        }
    }
}

// ===================== old 3-kernel path (ws mid-size fallback) =============
#define FEAT_BLOCKS 3125
#define WCONV_BLOCKS 16
#define FRONT_GRID  (BIN_BLOCKS + FEAT_BLOCKS + WCONV_BLOCKS)

__global__ __launch_bounds__(1024) void gcn_front(
    const float* __restrict__ feat, const float* __restrict__ W,
    const int* __restrict__ src, const int* __restrict__ dst,
    int* __restrict__ gcur, unsigned* __restrict__ bins,
    unsigned short* __restrict__ Wbf, float* __restrict__ out)
{
    __shared__ unsigned cnt[NBP2];
    __shared__ unsigned off[NBP2];
    __shared__ int      gbase[NBP2];
    __shared__ unsigned staged[CHUNK];
    __shared__ unsigned short sbk[CHUNK];
    __shared__ unsigned scan[1024];

    const int tid = threadIdx.x;
    const int bx  = blockIdx.x;

    if (bx >= BIN_BLOCKS) {
        const int rb = bx - BIN_BLOCKS;
        if (rb < FEAT_BLOCKS) {
            const int t = rb * 1024 + tid;
            const float4 v = *(const float4*)(feat + (size_t)t * 4);
            uint2 p;
            p.x = pack_bf16x2(v.x, v.y);
            p.y = pack_bf16x2(v.z, v.w);
            const int n = t >> 5, q = t & 31;
            *(uint2*)((char*)out + (size_t)n * 512 + q * 8) = p;
        } else {
            const int i = (rb - FEAT_BLOCKS) * 1024 + tid;
            Wbf[i] = f32_to_bf16(W[i]);
        }
        return;
    }

    const int e0 = bx * CHUNK;

    #pragma unroll
    for (int i = 0; i < 2; ++i) cnt[tid + i * 1024] = 0;
    __syncthreads();

    int sv[8], dv[8];
    #pragma unroll
    for (int i = 0; i < 8; ++i) {
        const int e = e0 + tid + i * 1024;
        if (e < N_EDGES) {
            sv[i] = src[e];
            dv[i] = dst[e];
            atomicAdd(&cnt[dv[i] >> 6], 1u);
        } else dv[i] = -1;
    }
    __syncthreads();

    const unsigned s = cnt[2 * tid] + cnt[2 * tid + 1];
    scan[tid] = s;
    __syncthreads();
    for (int o = 1; o < 1024; o <<= 1) {
        const unsigned t = (tid >= o) ? scan[tid - o] : 0;
        __syncthreads();
        scan[tid] += t;
        __syncthreads();
    }
    const unsigned run = scan[tid] - s;
    off[2 * tid]     = run;
    off[2 * tid + 1] = run + cnt[2 * tid];
    __syncthreads();

    #pragma unroll
    for (int i = 0; i < 8; ++i) {
        if (dv[i] >= 0) {
            const int bk = dv[i] >> 6;
            const unsigned w = (unsigned)sv[i] | ((unsigned)(dv[i] & 63) << 17);
            const unsigned p = atomicAdd(&off[bk], 1u);
            staged[p] = w;
            sbk[p] = (unsigned short)bk;
        }
    }
    __syncthreads();

    #pragma unroll
    for (int i = 0; i < 2; ++i) {
        const int bk = 2 * tid + i;
        if (bk < NB && cnt[bk] > 0)
            gbase[bk] = atomicAdd(&gcur[bk], (int)cnt[bk]);
    }
    __syncthreads();

    const int c_tot = (int)scan[1023];
    for (int p = tid; p < c_tot; p += 1024) {
        const int bk = sbk[p];
        const int gp = gbase[bk] + (p - (int)(off[bk] - cnt[bk]));
        if (gp < CAP) bins[(size_t)bk * CAP + gp] = staged[p];
    }
}

__global__ __launch_bounds__(512) void gcn_accum2(
    const int* __restrict__ gcur,
    const unsigned* __restrict__ bins,
    float* __restrict__ out)
{
    __shared__ unsigned tmp[CAP];
    __shared__ unsigned list[CAP];
    __shared__ int cnt64[64], scn[64], pos64[64], cur64[64];

    const int tid = threadIdx.x;
    const int bkt = blockIdx.x;

    int c = gcur[bkt]; if (c > CAP) c = CAP;
    const unsigned* bb = bins + (size_t)bkt * CAP;

    for (int i = tid; i < c; i += 512) tmp[i] = bb[i];
    if (tid < 64) cnt64[tid] = 0;
    __syncthreads();

    for (int i = tid; i < c; i += 512) atomicAdd(&cnt64[(tmp[i] >> 17) & 63], 1);
    __syncthreads();

    if (tid < 64) scn[tid] = cnt64[tid];
    __syncthreads();
    #pragma unroll
    for (int o = 1; o < 64; o <<= 1) {
        int t = 0;
        if (tid < 64 && tid >= o) t = scn[tid - o];
        __syncthreads();
        if (tid < 64) scn[tid] += t;
        __syncthreads();
    }
    if (tid < 64) {
        const int st = scn[tid] - cnt64[tid];
        pos64[tid] = st;
        cur64[tid] = st;
    }
    __syncthreads();

    for (int i = tid; i < c; i += 512) {
        const unsigned w = tmp[i];
        const int p = atomicAdd(&cur64[(w >> 17) & 63], 1);
        list[p] = w;
    }
    __syncthreads();

    const int grp = tid >> 4;
    const int sl  = tid & 15;
    const int n0  = bkt * 64;

    #pragma unroll
    for (int ni = 0; ni < 2; ++ni) {
        const int l  = grp * 2 + ni;
        const int st = pos64[l];
        const int en = st + cnt64[l];

        float a0[8] = {0,0,0,0,0,0,0,0};
        float a1[8] = {0,0,0,0,0,0,0,0};
        int k = st;
        for (; k + 3 < en; k += 4) {
            const unsigned w0 = list[k],     w1 = list[k + 1];
            const unsigned w2 = list[k + 2], w3 = list[k + 3];
            const uint4 v0 = *(const uint4*)((const char*)out + (size_t)(w0 & 0x1FFFF) * 512 + sl * 16);
            const uint4 v1 = *(const uint4*)((const char*)out + (size_t)(w1 & 0x1FFFF) * 512 + sl * 16);
            const uint4 v2 = *(const uint4*)((const char*)out + (size_t)(w2 & 0x1FFFF) * 512 + sl * 16);
            const uint4 v3 = *(const uint4*)((const char*)out + (size_t)(w3 & 0x1FFFF) * 512 + sl * 16);
            addrow(a0, v0); addrow(a1, v1); addrow(a0, v2); addrow(a1, v3);
        }
        for (; k < en; ++k) {
            const unsigned w0 = list[k];
            const uint4 v0 = *(const uint4*)((const char*)out + (size_t)(w0 & 0x1FFFF) * 512 + sl * 16);
            addrow(a0, v0);
        }
        #pragma unroll
        for (int q = 0; q < 8; ++q) a0[q] += a1[q];

        const int n = n0 + l;
        if (n < N_NODES) {
            uint4 o;
            o.x = pack_bf16x2(a0[0], a0[1]);
            o.y = pack_bf16x2(a0[2], a0[3]);
            o.z = pack_bf16x2(a0[4], a0[5]);
            o.w = pack_bf16x2(a0[6], a0[7]);
            *(uint4*)((char*)out + (size_t)n * 512 + 256 + sl * 16) = o;
        }
    }
}

#define MT   128

__global__ __launch_bounds__(256) void gcn_gemm_mfma(
    float* __restrict__ out,
    const unsigned short* __restrict__ Wbf,
    const float* __restrict__ b)
{
    __shared__ unsigned short Alds[MT * LDP];
    __shared__ unsigned short Wlds[F * LDP];

    const int tid  = threadIdx.x;
    const int row0 = blockIdx.x * MT;

    #pragma unroll
    for (int i = 0; i < 8; ++i) {
        const int c = tid + i * 256;
        const int r = c >> 4, cc = c & 15;
        *(uint4*)&Wlds[r * LDP + cc * 8] = *(const uint4*)&Wbf[c * 8];
    }
    #pragma unroll
    for (int i = 0; i < 8; ++i) {
        const int c = tid + i * 256;
        const int r = c >> 4, cc = c & 15;
        int gr = row0 + r; if (gr > N_NODES - 1) gr = N_NODES - 1;
        const uint4 v = *(const uint4*)((const char*)out + (size_t)gr * 512 + 256 + cc * 16);
        *(uint4*)&Alds[r * LDP + cc * 8] = v;
    }
    __syncthreads();

    const int lane = tid & 63;
    const int wv   = tid >> 6;
    const int lr   = lane & 15;
    const int lq   = lane >> 4;

    f32x4 acc[2][8] = {};
    #pragma unroll
    for (int kk = 0; kk < 4; ++kk) {
        bf16x8 a[2], w[8];
        #pragma unroll
        for (int i = 0; i < 2; ++i)
            a[i] = __builtin_bit_cast(bf16x8,
                *(const uint4*)&Alds[(wv * 32 + i * 16 + lr) * LDP + kk * 32 + lq * 8]);
        #pragma unroll
        for (int n = 0; n < 8; ++n)
            w[n] = __builtin_bit_cast(bf16x8,
                *(const uint4*)&Wlds[(n * 16 + lr) * LDP + kk * 32 + lq * 8]);
        #pragma unroll
        for (int i = 0; i < 2; ++i)
            #pragma unroll
            for (int n = 0; n < 8; ++n)
                acc[i][n] = __builtin_amdgcn_mfma_f32_16x16x32_bf16(a[i], w[n], acc[i][n], 0, 0, 0);
    }

    float bias[8];
    #pragma unroll
    for (int n = 0; n < 8; ++n) bias[n] = b[n * 16 + lr];

    #pragma unroll
    for (int i = 0; i < 2; ++i) {
        const int rbase = wv * 32 + i * 16 + lq * 4;
        #pragma unroll
        for (int rg = 0; rg < 4; ++rg) {
            const int gr = row0 + rbase + rg;
            if (gr < N_NODES) {
                float* orow = out + (size_t)gr * F;
                #pragma unroll
                for (int n = 0; n < 8; ++n) {
                    const float v = acc[i][n][rg] + bias[n];
                    orow[n * 16 + lr] = v > 0.0f ? v : 0.0f;
                }
            }
        }
    }
}

// ===================== fallback path (ws too small) =========================
__global__ __launch_bounds__(256) void gcn_scatter(
    const float* __restrict__ feat,
    const int* __restrict__ src, const int* __restrict__ dst,
    float* __restrict__ agg)
{
    const int sub  = threadIdx.x >> 5;
    const int lane = threadIdx.x & 31;
    const long long e = (long long)blockIdx.x * 8 + sub;
    if (e >= N_EDGES) return;
    const int s = src[e], d = dst[e];
    const float4 v = *(const float4*)(feat + (size_t)s * F + lane * 4);
    float* ar = agg + (size_t)d * F + lane * 4;
    unsafeAtomicAdd(ar + 0, v.x);
    unsafeAtomicAdd(ar + 1, v.y);
    unsafeAtomicAdd(ar + 2, v.z);
    unsafeAtomicAdd(ar + 3, v.w);
}

#define GR  64
#define LDW 132
__global__ __launch_bounds__(256) void gcn_gemm_relu(
    float* __restrict__ agg_out,
    const float* __restrict__ W, const float* __restrict__ b)
{
    __shared__ float Wl[F][LDW];
    __shared__ float At[GR][LDW];
    const int tid = threadIdx.x;
    const long long row0 = (long long)blockIdx.x * GR;
    #pragma unroll
    for (int i = 0; i < 64; ++i) {
        const int e = tid + i * 256;
        Wl[e >> 7][e & 127] = W[e];
    }
    #pragma unroll
    for (int i = 0; i < 32; ++i) {
        const int e = tid + i * 256;
        const int r = e >> 7, k2 = e & 127;
        const long long gr = row0 + r;
        At[r][k2] = (gr < N_NODES) ? agg_out[gr * F + k2] : 0.0f;
    }
    __syncthreads();
    const int tx = tid & 15, ty = tid >> 4, r0 = ty * 4;
    float acc[4][8];
    #pragma unroll
    for (int r = 0; r < 4; ++r)
        #pragma unroll
        for (int m = 0; m < 8; ++m) acc[r][m] = 0.0f;
    for (int k0 = 0; k0 < F; k0 += 4) {
        float4 a[4], w[8];
        #pragma unroll
        for (int r = 0; r < 4; ++r) a[r] = *(const float4*)&At[r0 + r][k0];
        #pragma unroll
        for (int m = 0; m < 8; ++m) w[m] = *(const float4*)&Wl[tx + 16 * m][k0];
        #pragma unroll
        for (int r = 0; r < 4; ++r)
            #pragma unroll
            for (int m = 0; m < 8; ++m)
                acc[r][m] += a[r].x * w[m].x + a[r].y * w[m].y
                           + a[r].z * w[m].z + a[r].w * w[m].w;
    }
    float bias[8];
    #pragma unroll
    for (int m = 0; m < 8; ++m) bias[m] = b[tx + 16 * m];
    __syncthreads();
    #pragma unroll
    for (int r = 0; r < 4; ++r) {
        const long long gr = row0 + r0 + r;
        if (gr < N_NODES) {
            float* orow = agg_out + gr * F;
            #pragma unroll
            for (int m = 0; m < 8; ++m) {
                const float v = acc[r][m] + bias[m];
                orow[tx + 16 * m] = v > 0.0f ? v : 0.0f;
            }
        }
    }
}

extern "C" void kernel_launch(void* const* d_in, const int* in_sizes, int n_in,
                              void* d_out, int out_size, void* d_ws, size_t ws_size,
                              hipStream_t stream) {
    const float* feat = (const float*)d_in[0];
    const int*   src  = (const int*)d_in[1];
    const int*   dst  = (const int*)d_in[2];
    const float* W    = (const float*)d_in[3];
    const float* b    = (const float*)d_in[4];
    float* out = (float*)d_out;

    // lin path ws: gcur[1600 ints] | bins[NB2*CAP2 uints] | H[N*F bf16]
    const size_t ws_lin = 1600u * 4 + (size_t)NB2 * CAP2 * 4 + (size_t)N_NODES * F * 2;
    // old path: gcur | bins[NB*CAP] | Wbf
    const size_t ws_old = 1600u * 4 + (size_t)NB * CAP * 4 + (size_t)F * F * 2;

    if (ws_size >= ws_lin) {
        int* gcur = (int*)d_ws;
        unsigned* bins = (unsigned*)(gcur + 1600);
        unsigned short* H = (unsigned short*)(bins + (size_t)NB2 * CAP2);

        hipMemsetAsync(gcur, 0, 1600 * sizeof(int), stream);
        gcn_front_lin<<<FRONT_GRID_LIN, 1024, 0, stream>>>(feat, W, src, dst, gcur, bins, H);
        gcn_accum_lin<<<NB2, 512, 0, stream>>>(gcur, bins, H, b, out);
    } else if (ws_size >= ws_old) {
        int* gcur = (int*)d_ws;
        unsigned* bins = (unsigned*)(gcur + 1600);
        unsigned short* Wbf = (unsigned short*)(bins + (size_t)NB * CAP);

        hipMemsetAsync(gcur, 0, NB * sizeof(int), stream);
        gcn_front   <<<FRONT_GRID, 1024, 0, stream>>>(feat, W, src, dst, gcur, bins, Wbf, out);
        gcn_accum2  <<<NB, 512, 0, stream>>>(gcur, bins, out);
        gcn_gemm_mfma<<<(N_NODES + MT - 1) / MT, 256, 0, stream>>>(out, Wbf, b);
    } else {
        hipMemsetAsync(out, 0, (size_t)N_NODES * F * sizeof(float), stream);
        gcn_scatter<<<N_EDGES / 8, 256, 0, stream>>>(feat, src, dst, out);
        gcn_gemm_relu<<<(N_NODES + GR - 1) / GR, 256, 0, stream>>>(out, W, b);
    }
}